// Round 11
// baseline (1133.231 us; speedup 1.0000x reference)
//
#include <hip/hip_runtime.h>
#include <hip/hip_bf16.h>
#include <math.h>

#define NN 8192
#define EE 131072
#define HH 256
#define LL 3
#define RR 128
#define NGG 64

typedef __attribute__((ext_vector_type(8))) short bf16x8;
typedef __attribute__((ext_vector_type(4))) float f32x4;
typedef unsigned short u16;

union U4 { ushort4 v; unsigned short a[4]; };
union U8 { uint4 v; unsigned short a[8]; };

__device__ __forceinline__ float silu(float v) { return v / (1.0f + expf(-v)); }
__device__ __forceinline__ float b2f(unsigned short u) { return __uint_as_float(((unsigned)u) << 16); }
__device__ __forceinline__ unsigned short f2b(float f) {
    unsigned u = __float_as_uint(f);
    u += 0x7fff + ((u >> 16) & 1);
    return (unsigned short)(u >> 16);
}

constexpr float kInvSqrt2 = 0.70710678118654752440f;
constexpr float kInvSqrt3 = 0.57735026918962576451f;
constexpr float kInvSqrtH = 0.0625f; // 1/sqrt(256)

// ---------------- utility ----------------
__global__ void k_zero(float* __restrict__ p, int n4) {
    int i = blockIdx.x * 256 + threadIdx.x;
    if (i < n4) ((float4*)p)[i] = make_float4(0.f, 0.f, 0.f, 0.f);
}

// ---------------- ALL weight prep in one launch ----------------
// transpose in[K,N] fp32 -> out[N,K] bf16; rbf_w: row-PAIR interleaved bf16
// Wp[(k>>1)*1536 + n*2 + (k&1)]  (for 16B paired loads in k_msg)
__global__ __launch_bounds__(256) void k_wt_all(
    const float* __restrict__ xp_w1, const float* __restrict__ xp_w2,
    const float* __restrict__ rbf_w, const float* __restrict__ vec_w,
    const float* __restrict__ xv_w1, const float* __restrict__ xv_w2,
    const float* __restrict__ oe_w1,
    u16* __restrict__ xp_w1T, u16* __restrict__ xp_w2T, u16* __restrict__ rbf_wP,
    u16* __restrict__ vec_wT, u16* __restrict__ xv_w1T, u16* __restrict__ xv_w2T,
    u16* __restrict__ oe_w1T) {
    int bid = blockIdx.x;
    const float* src; u16* dst; int K, N, t, pairmode = 0;
    if (bid < 2400) {
        int l = bid / 800, r = bid % 800;
        if (r < 64)       { src = xp_w1 + (size_t)l * 65536;  dst = xp_w1T + (size_t)l * 65536;  K = 256; N = 256; t = r; }
        else if (r < 256) { src = xp_w2 + (size_t)l * 196608; dst = xp_w2T + (size_t)l * 196608; K = 256; N = 768; t = r - 64; }
        else if (r < 352) { src = rbf_w + (size_t)l * 98304;  dst = rbf_wP + (size_t)l * 98304;  K = 128; N = 768; t = r - 256; pairmode = 1; }
        else if (r < 480) { src = vec_w + (size_t)l * 131072; dst = vec_wT + (size_t)l * 131072; K = 256; N = 512; t = r - 352; }
        else if (r < 608) { src = xv_w1 + (size_t)l * 131072; dst = xv_w1T + (size_t)l * 131072; K = 512; N = 256; t = r - 480; }
        else              { src = xv_w2 + (size_t)l * 196608; dst = xv_w2T + (size_t)l * 196608; K = 256; N = 768; t = r - 608; }
    } else {
        src = oe_w1; dst = oe_w1T; K = 256; N = 128; t = bid - 2400;
    }
    int nx = N >> 5;
    int bn = (t % nx) * 32, bk = (t / nx) * 32;
    int tx = threadIdx.x & 31, ty = threadIdx.x >> 5;   // 32 x 8
    if (pairmode) {
#pragma unroll
        for (int i = 0; i < 32; i += 8) {
            int k = bk + ty + i, n = bn + tx;
            dst[(size_t)(k >> 1) * 1536 + n * 2 + (k & 1)] = f2b(src[(size_t)k * N + n]);
        }
        return;
    }
    __shared__ float tile[32][33];
#pragma unroll
    for (int i = 0; i < 32; i += 8)
        tile[ty + i][tx] = src[(size_t)(bk + ty + i) * N + bn + tx];
    __syncthreads();
#pragma unroll
    for (int i = 0; i < 32; i += 8)
        dst[(size_t)(bn + ty + i) * K + bk + tx] = f2b(tile[tx][ty + i]);
}

// ---------------- init: x = atom_emb[z], + LayerNorm(ln[0]) -> xlnb ----------------
__global__ void k_init_ln(const float* __restrict__ emb, const int* __restrict__ z,
                          const float* __restrict__ w, const float* __restrict__ b,
                          float* __restrict__ x, u16* __restrict__ xlnb) {
    int n = blockIdx.x, t = threadIdx.x;
    float v = emb[z[n] * HH + t];
    x[(size_t)n * HH + t] = v;
    float s = v, q = v * v;
#pragma unroll
    for (int m = 32; m >= 1; m >>= 1) {
        s += __shfl_xor(s, m, 64);
        q += __shfl_xor(q, m, 64);
    }
    __shared__ float s_sum[4], s_sq[4];
    int wid = t >> 6;
    if ((t & 63) == 0) { s_sum[wid] = s; s_sq[wid] = q; }
    __syncthreads();
    float S = s_sum[0] + s_sum[1] + s_sum[2] + s_sum[3];
    float Q = s_sq[0] + s_sq[1] + s_sq[2] + s_sq[3];
    float mu = S * (1.0f / HH);
    float var = Q * (1.0f / HH) - mu * mu;
    float rs = rsqrtf(var + 1e-5f);
    xlnb[(size_t)n * HH + t] = f2b((v - mu) * rs * w[t] + b[t]);
}

// ---------------- edge geometry ----------------
__global__ void k_edge_geom(const float* __restrict__ pos, const int* __restrict__ ei,
                            float* __restrict__ ev /*[E,4]*/) {
    int e = blockIdx.x * 256 + threadIdx.x;
    if (e >= EE) return;
    int s = ei[e], d = ei[EE + e];
    float rx = pos[s * 3 + 0] - pos[d * 3 + 0];
    float ry = pos[s * 3 + 1] - pos[d * 3 + 1];
    float rz = pos[s * 3 + 2] - pos[d * 3 + 2];
    float dist = sqrtf(rx * rx + ry * ry + rz * rz);
    float inv = 1.0f / dist;
    ((float4*)ev)[e] = make_float4(rx * inv, ry * inv, rz * inv, dist);
}

// ---------------- CSR build ----------------
__global__ void k_hist(const int* __restrict__ ei, int* __restrict__ deg) {
    int e = blockIdx.x * 256 + threadIdx.x;
    if (e < EE) atomicAdd(&deg[ei[EE + e]], 1);
}
__global__ void k_scan(const int* __restrict__ deg, int* __restrict__ row_ptr,
                       int* __restrict__ fill) {
    __shared__ int buf[256];
    __shared__ int carry_s;
    int t = threadIdx.x;
    if (t == 0) carry_s = 0;
    __syncthreads();
    for (int r = 0; r < NN; r += 256) {
        int v = deg[r + t];
        buf[t] = v;
        __syncthreads();
        for (int ofs = 1; ofs < 256; ofs <<= 1) {
            int add = (t >= ofs) ? buf[t - ofs] : 0;
            __syncthreads();
            buf[t] += add;
            __syncthreads();
        }
        int excl = buf[t] - v;
        int carry = carry_s;
        row_ptr[r + t] = carry + excl;
        fill[r + t] = carry + excl;
        __syncthreads();
        if (t == 255) carry_s = carry + buf[t];
        __syncthreads();
    }
    if (t == 0) row_ptr[NN] = carry_s;
}
// scatter + packed src|k0pair + bf16 gaussian window (10 rows, even-aligned k0)
__global__ void k_scatter(const int* __restrict__ ei, const float* __restrict__ ev,
                          int* __restrict__ fill, int* __restrict__ srck,
                          float4* __restrict__ evp, u16* __restrict__ gtabB) {
    int e = blockIdx.x * 256 + threadIdx.x;
    if (e >= EE) return;
    int d = ei[EE + e];
    int pos = atomicAdd(&fill[d], 1);
    float4 e4 = ((const float4*)ev)[e];
    evp[pos] = e4;
    const float step = 12.0f / 127.0f;
    const float coeff = -0.5f / (step * step);
    float dist = e4.w;
    int k0 = ((int)floorf(dist / step) - 4) & ~1;
    k0 = k0 < 0 ? 0 : (k0 > 118 ? 118 : k0);
    srck[pos] = ei[e] | ((k0 >> 1) << 16);
    u16* gp = gtabB + (size_t)pos * 16;
#pragma unroll
    for (int k = 0; k < 10; ++k) {
        float t = dist - (k0 + k) * step;
        gp[k] = f2b(expf(coeff * t * t));
    }
}

// ---------------- bf16 MFMA GEMM: C = act(A[M,K] @ BT[N,K]^T + bias) ----------------
template <int AF32, int OUT_BF16, int ACT>
__global__ __launch_bounds__(256) void k_gemm(
    const void* __restrict__ Av, const u16* __restrict__ BT,
    const float* __restrict__ bias, void* __restrict__ C, int M, int K, int N) {
    __shared__ uint4 As4[512];
    __shared__ uint4 Bs4[512];
    u16* As = (u16*)As4;
    u16* Bs = (u16*)Bs4;
    int tid = threadIdx.x;
    int wave = tid >> 6, lane = tid & 63;
    int bm = blockIdx.y * 128, bn = blockIdx.x * 128;
    int wm = (wave >> 1) * 64, wn = (wave & 1) * 64;
    int lm = lane & 15;
    int kg = lane >> 4;
    f32x4 acc[4][4] = {};

    for (int k0 = 0; k0 < K; k0 += 32) {
#pragma unroll
        for (int it = 0; it < 2; ++it) {
            int idx = it * 256 + tid;
            int r = idx >> 2, seg = idx & 3;
            if (AF32) {
                const float* Af = (const float*)Av;
                float4 fa = *(const float4*)&Af[(size_t)(bm + r) * K + k0 + seg * 8];
                float4 fb = *(const float4*)&Af[(size_t)(bm + r) * K + k0 + seg * 8 + 4];
                U8 u;
                u.a[0] = f2b(fa.x); u.a[1] = f2b(fa.y); u.a[2] = f2b(fa.z); u.a[3] = f2b(fa.w);
                u.a[4] = f2b(fb.x); u.a[5] = f2b(fb.y); u.a[6] = f2b(fb.z); u.a[7] = f2b(fb.w);
                As4[idx] = u.v;
            } else {
                const u16* A = (const u16*)Av;
                As4[idx] = *(const uint4*)&A[(size_t)(bm + r) * K + k0 + seg * 8];
            }
            Bs4[idx] = *(const uint4*)&BT[(size_t)(bn + r) * K + k0 + seg * 8];
        }
        __syncthreads();
        bf16x8 af[4], bfr[4];
#pragma unroll
        for (int i = 0; i < 4; ++i)
            af[i] = *(const bf16x8*)&As[(wm + i * 16 + lm) * 32 + kg * 8];
#pragma unroll
        for (int j = 0; j < 4; ++j)
            bfr[j] = *(const bf16x8*)&Bs[(wn + j * 16 + lm) * 32 + kg * 8];
#pragma unroll
        for (int i = 0; i < 4; ++i)
#pragma unroll
            for (int j = 0; j < 4; ++j)
                acc[i][j] = __builtin_amdgcn_mfma_f32_16x16x32_bf16(af[i], bfr[j], acc[i][j], 0, 0, 0);
        __syncthreads();
    }

#pragma unroll
    for (int j = 0; j < 4; ++j) {
        int col = bn + wn + j * 16 + lm;
        float bv = bias ? bias[col] : 0.f;
#pragma unroll
        for (int i = 0; i < 4; ++i) {
            int row0 = bm + wm + i * 16 + kg * 4;
#pragma unroll
            for (int r = 0; r < 4; ++r) {
                float v = acc[i][j][r] + bv;
                if (ACT) v = silu(v);
                if (OUT_BF16)
                    ((u16*)C)[(size_t)(row0 + r) * N + col] = f2b(v);
                else
                    ((float*)C)[(size_t)(row0 + r) * N + col] = v;
            }
        }
    }
}

// ---------------- fused message pass v6: persistent waves + dynamic dst queue ------
// One wave per dst pulled from a global counter (load-balanced, sustained occupancy).
// W in row-pair layout: 15 x 16B coalesced loads/edge; 10-row even-aligned window.
__global__ __launch_bounds__(256) void k_msg(
    const u16* __restrict__ xhb, const u16* __restrict__ vinb,
    const int* __restrict__ srck, const float4* __restrict__ evp,
    const int* __restrict__ row_ptr, const u16* __restrict__ gtabB,
    const u16* __restrict__ WP /*[64 pairs][768][2] bf16*/,
    const float* __restrict__ rbias, float* __restrict__ x,
    const float* __restrict__ vin, float* __restrict__ vecM,
    int* __restrict__ qctr) {
    int lane = threadIdx.x & 63;
    int c4 = lane * 4;
    float4 bb0 = ((const float4*)rbias)[lane];
    float4 bb1 = ((const float4*)(rbias + 256))[lane];
    float4 bb2 = ((const float4*)(rbias + 512))[lane];
    for (;;) {
        int d = 0;
        if (lane == 0) d = atomicAdd(qctr, 1);
        d = __shfl(d, 0);
        if (d >= NN) break;
        int e0 = row_ptr[d], e1 = row_ptr[d + 1];
        float accx[4] = {};
        float accv[3][4] = {};
        for (int j = e0; j < e1; ++j) {
            int sk = srck[j];
            int s = sk & 0xffff;
            int kp = sk >> 16;               // pair index, rows 2kp..2kp+9
            float4 ev4 = evp[j];
            U8 gA; gA.v = *(const uint4*)&gtabB[(size_t)j * 16];
            unsigned gB = *(const unsigned*)&gtabB[(size_t)j * 16 + 8];
            const u16* xr = xhb + (size_t)s * 768;
            const u16* vr = vinb + (size_t)s * 768;
            U4 X0, X1, X2, V0, V1, V2;   // gathers issued early
            X0.v = *(const ushort4*)(xr + c4);
            X1.v = *(const ushort4*)(xr + 256 + c4);
            X2.v = *(const ushort4*)(xr + 512 + c4);
            V0.v = *(const ushort4*)(vr + c4);
            V1.v = *(const ushort4*)(vr + 256 + c4);
            V2.v = *(const ushort4*)(vr + 512 + c4);
            float g[10];
#pragma unroll
            for (int k = 0; k < 8; ++k) g[k] = b2f(gA.a[k]);
            g[8] = b2f((u16)(gB & 0xffff));
            g[9] = b2f((u16)(gB >> 16));
            float r0[4] = {bb0.x, bb0.y, bb0.z, bb0.w};
            float r1[4] = {bb1.x, bb1.y, bb1.z, bb1.w};
            float r2[4] = {bb2.x, bb2.y, bb2.z, bb2.w};
#pragma unroll
            for (int p = 0; p < 5; ++p) {
                const u16* wb = WP + (size_t)(kp + p) * 1536;
                U8 w0, w1, w2;               // cols c4..c4+3 x rows {2(kp+p), +1}
                w0.v = *(const uint4*)&wb[c4 * 2];
                w1.v = *(const uint4*)&wb[512 + c4 * 2];
                w2.v = *(const uint4*)&wb[1024 + c4 * 2];
                float ge = g[2 * p], go = g[2 * p + 1];
#pragma unroll
                for (int c = 0; c < 4; ++c) {
                    r0[c] += ge * b2f(w0.a[2 * c]) + go * b2f(w0.a[2 * c + 1]);
                    r1[c] += ge * b2f(w1.a[2 * c]) + go * b2f(w1.a[2 * c + 1]);
                    r2[c] += ge * b2f(w2.a[2 * c]) + go * b2f(w2.a[2 * c + 1]);
                }
            }
#pragma unroll
            for (int c = 0; c < 4; ++c) {
                accx[c] += b2f(X0.a[c]) * r0[c];
                float m1 = b2f(X1.a[c]) * r1[c] * kInvSqrt3;
                float m2 = b2f(X2.a[c]) * r2[c];
                accv[0][c] += b2f(V0.a[c]) * m1 + m2 * ev4.x;
                accv[1][c] += b2f(V1.a[c]) * m1 + m2 * ev4.y;
                accv[2][c] += b2f(V2.a[c]) * m1 + m2 * ev4.z;
            }
        }
        // epilogue: x=(x+dx)/sqrt2 ; vecM = vin + dvec*invSqrtH
        size_t xi = (size_t)d * 256 + c4;
        float4 xv = *(const float4*)&x[xi];
        xv.x = (xv.x + accx[0]) * kInvSqrt2;
        xv.y = (xv.y + accx[1]) * kInvSqrt2;
        xv.z = (xv.z + accx[2]) * kInvSqrt2;
        xv.w = (xv.w + accx[3]) * kInvSqrt2;
        *(float4*)&x[xi] = xv;
#pragma unroll
        for (int k3 = 0; k3 < 3; ++k3) {
            size_t idx = (size_t)d * 768 + k3 * 256 + c4;
            float4 vv = *(const float4*)&vin[idx];
            vv.x += accv[k3][0] * kInvSqrtH;
            vv.y += accv[k3][1] * kInvSqrtH;
            vv.z += accv[k3][2] * kInvSqrtH;
            vv.w += accv[k3][3] * kInvSqrtH;
            *(float4*)&vecM[idx] = vv;
        }
    }
}

// ---------------- vec_dot + hcat(bf16) = [x, vnorm]; vp in bf16 -------------------
__global__ void k_vecdot(const u16* __restrict__ vp, const float* __restrict__ x,
                         float* __restrict__ vec_dot, u16* __restrict__ hcat) {
    int i = blockIdx.x * 256 + threadIdx.x;  // N*H
    int n = i >> 8, c = i & 255;
    const u16* p = vp + (size_t)n * 1536;
    float dsum = 0.f, qsum = 0.f;
#pragma unroll
    for (int k = 0; k < 3; ++k) {
        float v1 = b2f(p[k * 512 + c]);
        float v2 = b2f(p[k * 512 + 256 + c]);
        dsum += v1 * v2;
        qsum += v2 * v2;
    }
    vec_dot[i] = dsum * kInvSqrtH;
    hcat[(size_t)n * 512 + c] = f2b(x[i]);
    hcat[(size_t)n * 512 + 256 + c] = f2b(sqrtf(qsum + 1e-8f));
}

// ---------------- update epilogue + fused LayerNorm for next layer ----------------
__global__ void k_update_out(const u16* __restrict__ hout, const float* __restrict__ vec_dot,
                             const u16* __restrict__ vp, float* __restrict__ x,
                             const float* __restrict__ vecM, float* __restrict__ vfin,
                             u16* __restrict__ vb,
                             const float* __restrict__ lnw, const float* __restrict__ lnb,
                             u16* __restrict__ xout) {
    int n = blockIdx.x, t = threadIdx.x;
    size_t i = (size_t)n * 256 + t;
    float xv1 = b2f(hout[(size_t)n * 768 + t]);
    float xv2 = b2f(hout[(size_t)n * 768 + 256 + t]);
    float xv3 = b2f(hout[(size_t)n * 768 + 512 + t]);
    float dxv = (xv1 + xv2 * vec_dot[i]) * kInvSqrt2;
    float nx = (x[i] + dxv) * kInvSqrt2;
    x[i] = nx;
#pragma unroll
    for (int k = 0; k < 3; ++k) {
        size_t idx = (size_t)n * 768 + k * 256 + t;
        float nv = vecM[idx] + xv3 * b2f(vp[(size_t)n * 1536 + k * 512 + t]);
        vfin[idx] = nv;
        vb[idx] = f2b(nv);
    }
    if (lnw) {
        float s = nx, q = nx * nx;
#pragma unroll
        for (int m = 32; m >= 1; m >>= 1) {
            s += __shfl_xor(s, m, 64);
            q += __shfl_xor(q, m, 64);
        }
        __shared__ float s_sum[4], s_sq[4];
        int wid = t >> 6;
        if ((t & 63) == 0) { s_sum[wid] = s; s_sq[wid] = q; }
        __syncthreads();
        float S = s_sum[0] + s_sum[1] + s_sum[2] + s_sum[3];
        float Q = s_sq[0] + s_sq[1] + s_sq[2] + s_sq[3];
        float mu = S * (1.0f / HH);
        float var = Q * (1.0f / HH) - mu * mu;
        float rs = rsqrtf(var + 1e-5f);
        xout[i] = f2b((nx - mu) * rs * lnw[t] + lnb[t]);
    } else {
        xout[i] = f2b(nx);
    }
}

// ---------------- energy reduce ----------------
__global__ void k_energy2(const float* __restrict__ h, const float* __restrict__ w2,
                          const float* __restrict__ b2, const int* __restrict__ batch,
                          float* __restrict__ out) {
    __shared__ float g[NGG];
    int t = threadIdx.x;
    if (t < NGG) g[t] = 0.f;
    __syncthreads();
    int a = blockIdx.x * 256 + t;
    const float4* hr = (const float4*)(h + (size_t)a * 128);
    const float4* w4 = (const float4*)w2;
    float acc = 0.f;
#pragma unroll 8
    for (int i = 0; i < 32; ++i) {
        float4 hv = hr[i], wv = w4[i];
        acc += hv.x * wv.x + hv.y * wv.y + hv.z * wv.z + hv.w * wv.w;
    }
    acc += b2[0];
    atomicAdd(&g[batch[a]], acc);
    __syncthreads();
    if (t < NGG && g[t] != 0.f) atomicAdd(&out[t], g[t]);
}

extern "C" void kernel_launch(void* const* d_in, const int* in_sizes, int n_in,
                              void* d_out, int out_size, void* d_ws, size_t ws_size,
                              hipStream_t stream) {
    const float* pos      = (const float*)d_in[0];
    const float* atom_emb = (const float*)d_in[1];
    const float* ln_w     = (const float*)d_in[2];
    const float* ln_b     = (const float*)d_in[3];
    const float* xp_w1    = (const float*)d_in[4];
    const float* xp_b1    = (const float*)d_in[5];
    const float* xp_w2    = (const float*)d_in[6];
    const float* xp_b2    = (const float*)d_in[7];
    const float* rbf_w    = (const float*)d_in[8];
    const float* rbf_b    = (const float*)d_in[9];
    const float* vec_w    = (const float*)d_in[10];
    const float* xv_w1    = (const float*)d_in[11];
    const float* xv_b1    = (const float*)d_in[12];
    const float* xv_w2    = (const float*)d_in[13];
    const float* xv_b2    = (const float*)d_in[14];
    const float* oe_w1    = (const float*)d_in[15];
    const float* oe_b1    = (const float*)d_in[16];
    const float* oe_w2    = (const float*)d_in[17];
    const float* oe_b2    = (const float*)d_in[18];
    const int*   z        = (const int*)d_in[19];
    const int*   ei       = (const int*)d_in[20];
    const int*   batch    = (const int*)d_in[21];
    float* out = (float*)d_out;

    char* ws = (char*)d_ws;
    size_t off = 0;
    auto alloc = [&](size_t b) {
        void* p = ws + off;
        off = (off + b + 255) & ~(size_t)255;
        return p;
    };
    float*  x      = (float*)alloc((size_t)NN * HH * 4);       //   8 MB
    float*  vecA   = (float*)alloc((size_t)NN * 768 * 4);      //  24 MB  \ adjacent:
    u16*    vb     = (u16*)alloc((size_t)NN * 768 * 2);        //  12 MB  / joint zero
    float*  vecM   = (float*)alloc((size_t)NN * 768 * 4);      //  24 MB
    u16*    xlnb   = (u16*)alloc((size_t)NN * HH * 2);         //   4 MB (alias xb)
    u16*    t1b    = (u16*)alloc((size_t)NN * HH * 2);         //   4 MB (alias h1b)
    u16*    xhb    = (u16*)alloc((size_t)NN * 768 * 2);        //  12 MB (alias hcatb)
    float*  vdot   = (float*)alloc((size_t)NN * HH * 4);       //   8 MB (alias heng)
    u16*    vpb    = (u16*)alloc((size_t)NN * 1536 * 2);       //  24 MB
    u16*    houtb  = (u16*)alloc((size_t)NN * 768 * 2);        //  12 MB
    float*  ev     = (float*)alloc((size_t)EE * 4 * 4);        //   2 MB
    int*    deg    = (int*)alloc((size_t)NN * 4);
    int*    row_ptr= (int*)alloc((size_t)(NN + 1) * 4);
    int*    fill   = (int*)alloc((size_t)NN * 4);
    int*    srck   = (int*)alloc((size_t)EE * 4);
    float4* evp    = (float4*)alloc((size_t)EE * 16);          //   2 MB
    u16*    gtabB  = (u16*)alloc((size_t)EE * 16 * 2);         //   4 MB
    int*    qctr   = (int*)alloc(256);                         // layer queues
    u16* xp_w1T   = (u16*)alloc((size_t)3 * 256 * 256 * 2);
    u16* xp_w2T   = (u16*)alloc((size_t)3 * 768 * 256 * 2);
    u16* rbf_wP   = (u16*)alloc((size_t)3 * 128 * 768 * 2);    // row-pair bf16
    u16* vec_wT   = (u16*)alloc((size_t)3 * 512 * 256 * 2);
    u16* xv_w1T   = (u16*)alloc((size_t)3 * 256 * 512 * 2);
    u16* xv_w2T   = (u16*)alloc((size_t)3 * 768 * 256 * 2);
    u16* oe_w1T   = (u16*)alloc((size_t)128 * 256 * 2);
    (void)ws_size;

    u16*   h1b   = t1b;
    u16*   hcatb = xhb;
    float* heng  = vdot;
    u16*   xb    = xlnb;

    // ---- setup ----
    k_wt_all<<<2432, 256, 0, stream>>>(xp_w1, xp_w2, rbf_w, vec_w, xv_w1, xv_w2, oe_w1,
                                       xp_w1T, xp_w2T, rbf_wP, vec_wT, xv_w1T, xv_w2T, oe_w1T);
    k_zero<<<(36 * 1024 * 1024 / 16 + 255) / 256, 256, 0, stream>>>(vecA, 36 * 1024 * 1024 / 16);
    k_zero<<<8, 256, 0, stream>>>((float*)deg, NN / 4);
    k_zero<<<1, 256, 0, stream>>>((float*)qctr, 16);
    k_init_ln<<<NN, 256, 0, stream>>>(atom_emb, z, ln_w, ln_b, x, xlnb);
    k_edge_geom<<<EE / 256, 256, 0, stream>>>(pos, ei, ev);
    k_hist<<<EE / 256, 256, 0, stream>>>(ei, deg);
    k_scan<<<1, 256, 0, stream>>>(deg, row_ptr, fill);
    k_scatter<<<EE / 256, 256, 0, stream>>>(ei, ev, fill, srck, evp, gtabB);

    for (int l = 0; l < LL; ++l) {
        // ---- PaiNNMessage ----
        k_gemm<0, 1, 1><<<dim3(2, NN / 128), 256, 0, stream>>>(
            xlnb, xp_w1T + (size_t)l * 256 * 256, xp_b1 + l * HH, t1b, NN, 256, 256);
        k_gemm<0, 1, 0><<<dim3(6, NN / 128), 256, 0, stream>>>(
            t1b, xp_w2T + (size_t)l * 768 * 256, xp_b2 + l * 768, xhb, NN, 256, 768);
        k_msg<<<1024, 256, 0, stream>>>(
            xhb, vb, srck, evp, row_ptr, gtabB,
            rbf_wP + (size_t)l * 128 * 768, rbf_b + l * 768, x, vecA, vecM,
            qctr + l * 16);

        // ---- PaiNNUpdate ----
        k_gemm<1, 1, 0><<<dim3(4, 3 * NN / 128), 256, 0, stream>>>(
            vecM, vec_wT + (size_t)l * 512 * 256, nullptr, vpb, 3 * NN, 256, 512);
        k_vecdot<<<NN, 256, 0, stream>>>(vpb, x, vdot, hcatb);
        k_gemm<0, 1, 1><<<dim3(2, NN / 128), 256, 0, stream>>>(
            hcatb, xv_w1T + (size_t)l * 256 * 512, xv_b1 + l * HH, h1b, NN, 512, 256);
        k_gemm<0, 1, 0><<<dim3(6, NN / 128), 256, 0, stream>>>(
            h1b, xv_w2T + (size_t)l * 768 * 256, xv_b2 + l * 768, houtb, NN, 256, 768);
        bool last = (l == LL - 1);
        k_update_out<<<NN, 256, 0, stream>>>(
            houtb, vdot, vpb, x, vecM, vecA, vb,
            last ? nullptr : ln_w + (l + 1) * HH,
            last ? nullptr : ln_b + (l + 1) * HH, xlnb);
    }

    // ---- energy head ----
    k_gemm<0, 0, 1><<<dim3(1, NN / 128), 256, 0, stream>>>(
        xb, oe_w1T, oe_b1, heng, NN, 256, 128);
    k_zero<<<1, 256, 0, stream>>>(out, NGG / 4);
    k_energy2<<<32, 256, 0, stream>>>(heng, oe_w2, oe_b2, batch, out);
}

// Round 12
// 1007.593 us; speedup vs baseline: 1.1247x; 1.1247x over previous
//
#include <hip/hip_runtime.h>
#include <hip/hip_bf16.h>
#include <math.h>

#define NN 8192
#define EE 131072
#define HH 256
#define LL 3
#define RR 128
#define NGG 64
#define DPW 2                // dsts per wave in k_msg
#define DPB (DPW * 4)        // dsts per block = 8

typedef __attribute__((ext_vector_type(8))) short bf16x8;
typedef __attribute__((ext_vector_type(4))) float f32x4;
typedef unsigned short u16;

union U4 { ushort4 v; unsigned short a[4]; };
union U8 { uint4 v; unsigned short a[8]; };

__device__ __forceinline__ float silu(float v) { return v / (1.0f + expf(-v)); }
__device__ __forceinline__ float b2f(unsigned short u) { return __uint_as_float(((unsigned)u) << 16); }
__device__ __forceinline__ unsigned short f2b(float f) {
    unsigned u = __float_as_uint(f);
    u += 0x7fff + ((u >> 16) & 1);
    return (unsigned short)(u >> 16);
}

constexpr float kInvSqrt2 = 0.70710678118654752440f;
constexpr float kInvSqrt3 = 0.57735026918962576451f;
constexpr float kInvSqrtH = 0.0625f; // 1/sqrt(256)

// ---------------- utility ----------------
__global__ void k_zero(float* __restrict__ p, int n4) {
    int i = blockIdx.x * 256 + threadIdx.x;
    if (i < n4) ((float4*)p)[i] = make_float4(0.f, 0.f, 0.f, 0.f);
}

// ---------------- ALL weight prep in one launch ----------------
// transpose in[K,N] fp32 -> out[N,K] bf16, except rbf_w: straight cast (k-major kept)
__global__ __launch_bounds__(256) void k_wt_all(
    const float* __restrict__ xp_w1, const float* __restrict__ xp_w2,
    const float* __restrict__ rbf_w, const float* __restrict__ vec_w,
    const float* __restrict__ xv_w1, const float* __restrict__ xv_w2,
    const float* __restrict__ oe_w1,
    u16* __restrict__ xp_w1T, u16* __restrict__ xp_w2T, u16* __restrict__ rbf_wKb,
    u16* __restrict__ vec_wT, u16* __restrict__ xv_w1T, u16* __restrict__ xv_w2T,
    u16* __restrict__ oe_w1T) {
    int bid = blockIdx.x;
    const float* src; u16* dst; int K, N, t, cast = 0;
    if (bid < 2400) {
        int l = bid / 800, r = bid % 800;
        if (r < 64)       { src = xp_w1 + (size_t)l * 65536;  dst = xp_w1T + (size_t)l * 65536;  K = 256; N = 256; t = r; }
        else if (r < 256) { src = xp_w2 + (size_t)l * 196608; dst = xp_w2T + (size_t)l * 196608; K = 256; N = 768; t = r - 64; }
        else if (r < 352) { src = rbf_w + (size_t)l * 98304;  dst = rbf_wKb + (size_t)l * 98304; K = 128; N = 768; t = r - 256; cast = 1; }
        else if (r < 480) { src = vec_w + (size_t)l * 131072; dst = vec_wT + (size_t)l * 131072; K = 256; N = 512; t = r - 352; }
        else if (r < 608) { src = xv_w1 + (size_t)l * 131072; dst = xv_w1T + (size_t)l * 131072; K = 512; N = 256; t = r - 480; }
        else              { src = xv_w2 + (size_t)l * 196608; dst = xv_w2T + (size_t)l * 196608; K = 256; N = 768; t = r - 608; }
    } else {
        src = oe_w1; dst = oe_w1T; K = 256; N = 128; t = bid - 2400;
    }
    int nx = N >> 5;
    int bn = (t % nx) * 32, bk = (t / nx) * 32;
    int tx = threadIdx.x & 31, ty = threadIdx.x >> 5;   // 32 x 8
    if (cast) {
#pragma unroll
        for (int i = 0; i < 32; i += 8)
            dst[(size_t)(bk + ty + i) * N + bn + tx] = f2b(src[(size_t)(bk + ty + i) * N + bn + tx]);
        return;
    }
    __shared__ float tile[32][33];
#pragma unroll
    for (int i = 0; i < 32; i += 8)
        tile[ty + i][tx] = src[(size_t)(bk + ty + i) * N + bn + tx];
    __syncthreads();
#pragma unroll
    for (int i = 0; i < 32; i += 8)
        dst[(size_t)(bn + ty + i) * K + bk + tx] = f2b(tile[tx][ty + i]);
}

// ---------------- init: x = atom_emb[z], + LayerNorm(ln[0]) -> xlnb ----------------
__global__ void k_init_ln(const float* __restrict__ emb, const int* __restrict__ z,
                          const float* __restrict__ w, const float* __restrict__ b,
                          float* __restrict__ x, u16* __restrict__ xlnb) {
    int n = blockIdx.x, t = threadIdx.x;
    float v = emb[z[n] * HH + t];
    x[(size_t)n * HH + t] = v;
    float s = v, q = v * v;
#pragma unroll
    for (int m = 32; m >= 1; m >>= 1) {
        s += __shfl_xor(s, m, 64);
        q += __shfl_xor(q, m, 64);
    }
    __shared__ float s_sum[4], s_sq[4];
    int wid = t >> 6;
    if ((t & 63) == 0) { s_sum[wid] = s; s_sq[wid] = q; }
    __syncthreads();
    float S = s_sum[0] + s_sum[1] + s_sum[2] + s_sum[3];
    float Q = s_sq[0] + s_sq[1] + s_sq[2] + s_sq[3];
    float mu = S * (1.0f / HH);
    float var = Q * (1.0f / HH) - mu * mu;
    float rs = rsqrtf(var + 1e-5f);
    xlnb[(size_t)n * HH + t] = f2b((v - mu) * rs * w[t] + b[t]);
}

// ---------------- edge geometry ----------------
__global__ void k_edge_geom(const float* __restrict__ pos, const int* __restrict__ ei,
                            float* __restrict__ ev /*[E,4]*/) {
    int e = blockIdx.x * 256 + threadIdx.x;
    if (e >= EE) return;
    int s = ei[e], d = ei[EE + e];
    float rx = pos[s * 3 + 0] - pos[d * 3 + 0];
    float ry = pos[s * 3 + 1] - pos[d * 3 + 1];
    float rz = pos[s * 3 + 2] - pos[d * 3 + 2];
    float dist = sqrtf(rx * rx + ry * ry + rz * rz);
    float inv = 1.0f / dist;
    ((float4*)ev)[e] = make_float4(rx * inv, ry * inv, rz * inv, dist);
}

// ---------------- CSR build ----------------
__global__ void k_hist(const int* __restrict__ ei, int* __restrict__ deg) {
    int e = blockIdx.x * 256 + threadIdx.x;
    if (e < EE) atomicAdd(&deg[ei[EE + e]], 1);
}
__global__ void k_scan(const int* __restrict__ deg, int* __restrict__ row_ptr,
                       int* __restrict__ fill) {
    __shared__ int buf[256];
    __shared__ int carry_s;
    int t = threadIdx.x;
    if (t == 0) carry_s = 0;
    __syncthreads();
    for (int r = 0; r < NN; r += 256) {
        int v = deg[r + t];
        buf[t] = v;
        __syncthreads();
        for (int ofs = 1; ofs < 256; ofs <<= 1) {
            int add = (t >= ofs) ? buf[t - ofs] : 0;
            __syncthreads();
            buf[t] += add;
            __syncthreads();
        }
        int excl = buf[t] - v;
        int carry = carry_s;
        row_ptr[r + t] = carry + excl;
        fill[r + t] = carry + excl;
        __syncthreads();
        if (t == 255) carry_s = carry + buf[t];
        __syncthreads();
    }
    if (t == 0) row_ptr[NN] = carry_s;
}
// scatter + fused per-edge gaussian window table (8 rows, k0 clamp [0,120])
__global__ void k_scatter(const int* __restrict__ ei, const float* __restrict__ ev,
                          int* __restrict__ fill, int* __restrict__ srcp,
                          float4* __restrict__ evp, int* __restrict__ k0tab,
                          float* __restrict__ gtab) {
    int e = blockIdx.x * 256 + threadIdx.x;
    if (e >= EE) return;
    int d = ei[EE + e];
    int pos = atomicAdd(&fill[d], 1);
    float4 e4 = ((const float4*)ev)[e];
    srcp[pos] = ei[e];
    evp[pos] = e4;
    const float step = 12.0f / 127.0f;
    const float coeff = -0.5f / (step * step);
    float dist = e4.w;
    int k0 = (int)floorf(dist / step) - 3;
    k0 = k0 < 0 ? 0 : (k0 > 120 ? 120 : k0);
    float g[8];
#pragma unroll
    for (int k = 0; k < 8; ++k) {
        float t = dist - (k0 + k) * step;
        g[k] = expf(coeff * t * t);
    }
    k0tab[pos] = k0;
    ((float4*)gtab)[pos * 2 + 0] = make_float4(g[0], g[1], g[2], g[3]);
    ((float4*)gtab)[pos * 2 + 1] = make_float4(g[4], g[5], g[6], g[7]);
}

// ---------------- bf16 MFMA GEMM: C = act(A[M,K] @ BT[N,K]^T + bias) ----------------
template <int AF32, int OUT_BF16, int ACT>
__global__ __launch_bounds__(256) void k_gemm(
    const void* __restrict__ Av, const u16* __restrict__ BT,
    const float* __restrict__ bias, void* __restrict__ C, int M, int K, int N) {
    __shared__ uint4 As4[512];
    __shared__ uint4 Bs4[512];
    u16* As = (u16*)As4;
    u16* Bs = (u16*)Bs4;
    int tid = threadIdx.x;
    int wave = tid >> 6, lane = tid & 63;
    int bm = blockIdx.y * 128, bn = blockIdx.x * 128;
    int wm = (wave >> 1) * 64, wn = (wave & 1) * 64;
    int lm = lane & 15;
    int kg = lane >> 4;
    f32x4 acc[4][4] = {};

    for (int k0 = 0; k0 < K; k0 += 32) {
#pragma unroll
        for (int it = 0; it < 2; ++it) {
            int idx = it * 256 + tid;
            int r = idx >> 2, seg = idx & 3;
            if (AF32) {
                const float* Af = (const float*)Av;
                float4 fa = *(const float4*)&Af[(size_t)(bm + r) * K + k0 + seg * 8];
                float4 fb = *(const float4*)&Af[(size_t)(bm + r) * K + k0 + seg * 8 + 4];
                U8 u;
                u.a[0] = f2b(fa.x); u.a[1] = f2b(fa.y); u.a[2] = f2b(fa.z); u.a[3] = f2b(fa.w);
                u.a[4] = f2b(fb.x); u.a[5] = f2b(fb.y); u.a[6] = f2b(fb.z); u.a[7] = f2b(fb.w);
                As4[idx] = u.v;
            } else {
                const u16* A = (const u16*)Av;
                As4[idx] = *(const uint4*)&A[(size_t)(bm + r) * K + k0 + seg * 8];
            }
            Bs4[idx] = *(const uint4*)&BT[(size_t)(bn + r) * K + k0 + seg * 8];
        }
        __syncthreads();
        bf16x8 af[4], bfr[4];
#pragma unroll
        for (int i = 0; i < 4; ++i)
            af[i] = *(const bf16x8*)&As[(wm + i * 16 + lm) * 32 + kg * 8];
#pragma unroll
        for (int j = 0; j < 4; ++j)
            bfr[j] = *(const bf16x8*)&Bs[(wn + j * 16 + lm) * 32 + kg * 8];
#pragma unroll
        for (int i = 0; i < 4; ++i)
#pragma unroll
            for (int j = 0; j < 4; ++j)
                acc[i][j] = __builtin_amdgcn_mfma_f32_16x16x32_bf16(af[i], bfr[j], acc[i][j], 0, 0, 0);
        __syncthreads();
    }

#pragma unroll
    for (int j = 0; j < 4; ++j) {
        int col = bn + wn + j * 16 + lm;
        float bv = bias ? bias[col] : 0.f;
#pragma unroll
        for (int i = 0; i < 4; ++i) {
            int row0 = bm + wm + i * 16 + kg * 4;
#pragma unroll
            for (int r = 0; r < 4; ++r) {
                float v = acc[i][j][r] + bv;
                if (ACT) v = silu(v);
                if (OUT_BF16)
                    ((u16*)C)[(size_t)(row0 + r) * N + col] = f2b(v);
                else
                    ((float*)C)[(size_t)(row0 + r) * N + col] = v;
            }
        }
    }
}

// ---------------- fused message pass v7: R8 structure + software-pipelined edges ---
// 3 panel passes (64KB LDS); per edge: prefetch next edge's global loads before
// this edge's ds_read+FMA combine (double memory-level parallelism per wave).
__global__ __launch_bounds__(256) void k_msg(
    const u16* __restrict__ xhb, const u16* __restrict__ vinb,
    const int* __restrict__ srcp, const float4* __restrict__ evp,
    const int* __restrict__ row_ptr, const int* __restrict__ k0tab,
    const float* __restrict__ gtab, const u16* __restrict__ WK /*[128][768] bf16*/,
    const float* __restrict__ rbias, float* __restrict__ x,
    const float* __restrict__ vin, float* __restrict__ vecM) {
    __shared__ u16 Wp[128 * 256];   // 64 KB panel
    int tid = threadIdx.x;
    int wave = tid >> 6, lane = tid & 63;
    int c0 = lane * 4;
    int dbase = blockIdx.x * DPB + wave * DPW;
    float accv[DPW][3][4] = {};     // persists across panels 1,2

#pragma unroll
    for (int p = 0; p < 3; ++p) {
        __syncthreads();
#pragma unroll 4
        for (int it = 0; it < 16; ++it) {        // cooperative 64KB panel load
            int idx = it * 256 + tid;
            int row = idx >> 5;
            int col8 = (idx & 31) * 8;
            *(uint4*)&Wp[row * 256 + col8] =
                *(const uint4*)&WK[(size_t)row * 768 + p * 256 + col8];
        }
        __syncthreads();
        float4 bb = ((const float4*)(rbias + p * 256))[lane];
        float bias4[4] = {bb.x, bb.y, bb.z, bb.w};
#pragma unroll
        for (int dd = 0; dd < DPW; ++dd) {
            int d = dbase + dd;
            int E0 = row_ptr[d], E1 = row_ptr[d + 1];
            float accx[4] = {};
            if (E0 < E1) {
                // ---- prologue: load edge E0's data ----
                int sj = srcp[E0];
                int kj = k0tab[E0];
                float4 gaj = ((const float4*)gtab)[(size_t)E0 * 2 + 0];
                float4 gbj = ((const float4*)gtab)[(size_t)E0 * 2 + 1];
                U4 Xj, Vj0, Vj1, Vj2;
                float4 evj = make_float4(0.f, 0.f, 0.f, 0.f);
                if (p == 0) {
                    Xj.v = *(const ushort4*)(xhb + (size_t)sj * 768 + c0);
                } else if (p == 1) {
                    Xj.v = *(const ushort4*)(xhb + (size_t)sj * 768 + 256 + c0);
                    Vj0.v = *(const ushort4*)(vinb + (size_t)sj * 768 + c0);
                    Vj1.v = *(const ushort4*)(vinb + (size_t)sj * 768 + 256 + c0);
                    Vj2.v = *(const ushort4*)(vinb + (size_t)sj * 768 + 512 + c0);
                } else {
                    Xj.v = *(const ushort4*)(xhb + (size_t)sj * 768 + 512 + c0);
                    evj = evp[E0];
                }
                for (int j = E0; j < E1; ++j) {
                    // ---- prefetch edge j+1 (clamped; redundant reload on last) ----
                    int jn = (j + 1 < E1) ? j + 1 : j;
                    int sn = srcp[jn];
                    int kn = k0tab[jn];
                    float4 gan = ((const float4*)gtab)[(size_t)jn * 2 + 0];
                    float4 gbn = ((const float4*)gtab)[(size_t)jn * 2 + 1];
                    U4 Xn, Vn0, Vn1, Vn2;
                    float4 evn = make_float4(0.f, 0.f, 0.f, 0.f);
                    if (p == 0) {
                        Xn.v = *(const ushort4*)(xhb + (size_t)sn * 768 + c0);
                    } else if (p == 1) {
                        Xn.v = *(const ushort4*)(xhb + (size_t)sn * 768 + 256 + c0);
                        Vn0.v = *(const ushort4*)(vinb + (size_t)sn * 768 + c0);
                        Vn1.v = *(const ushort4*)(vinb + (size_t)sn * 768 + 256 + c0);
                        Vn2.v = *(const ushort4*)(vinb + (size_t)sn * 768 + 512 + c0);
                    } else {
                        Xn.v = *(const ushort4*)(xhb + (size_t)sn * 768 + 512 + c0);
                        evn = evp[jn];
                    }
                    // ---- compute with edge j's registers ----
                    float g[8] = {gaj.x, gaj.y, gaj.z, gaj.w, gbj.x, gbj.y, gbj.z, gbj.w};
                    float rr[4] = {bias4[0], bias4[1], bias4[2], bias4[3]};
#pragma unroll
                    for (int k = 0; k < 8; ++k) {
                        U4 w;
                        w.v = *(const ushort4*)&Wp[(kj + k) * 256 + c0];
#pragma unroll
                        for (int c = 0; c < 4; ++c) rr[c] += g[k] * b2f(w.a[c]);
                    }
                    if (p == 0) {
#pragma unroll
                        for (int c = 0; c < 4; ++c) accx[c] += b2f(Xj.a[c]) * rr[c];
                    } else if (p == 1) {
#pragma unroll
                        for (int c = 0; c < 4; ++c) {
                            float m1 = b2f(Xj.a[c]) * rr[c] * kInvSqrt3;
                            accv[dd][0][c] += b2f(Vj0.a[c]) * m1;
                            accv[dd][1][c] += b2f(Vj1.a[c]) * m1;
                            accv[dd][2][c] += b2f(Vj2.a[c]) * m1;
                        }
                    } else {
#pragma unroll
                        for (int c = 0; c < 4; ++c) {
                            float m2 = b2f(Xj.a[c]) * rr[c];
                            accv[dd][0][c] += m2 * evj.x;
                            accv[dd][1][c] += m2 * evj.y;
                            accv[dd][2][c] += m2 * evj.z;
                        }
                    }
                    // ---- rotate ----
                    sj = sn; kj = kn; gaj = gan; gbj = gbn;
                    Xj = Xn; Vj0 = Vn0; Vj1 = Vn1; Vj2 = Vn2; evj = evn;
                }
            }
            if (p == 0) {
                size_t xi = (size_t)d * 256 + c0;
                float4 xv = *(const float4*)&x[xi];
                xv.x = (xv.x + accx[0]) * kInvSqrt2;
                xv.y = (xv.y + accx[1]) * kInvSqrt2;
                xv.z = (xv.z + accx[2]) * kInvSqrt2;
                xv.w = (xv.w + accx[3]) * kInvSqrt2;
                *(float4*)&x[xi] = xv;
            }
        }
    }
    // epilogue: vecM = vin + dvec * invSqrtH
#pragma unroll
    for (int dd = 0; dd < DPW; ++dd) {
        int d = dbase + dd;
#pragma unroll
        for (int k = 0; k < 3; ++k) {
            size_t idx = (size_t)d * 768 + k * 256 + c0;
            float4 vv = *(const float4*)&vin[idx];
            vv.x += accv[dd][k][0] * kInvSqrtH;
            vv.y += accv[dd][k][1] * kInvSqrtH;
            vv.z += accv[dd][k][2] * kInvSqrtH;
            vv.w += accv[dd][k][3] * kInvSqrtH;
            *(float4*)&vecM[idx] = vv;
        }
    }
}

// ---------------- vec_dot + hcat(bf16) = [x, vnorm]; vp in bf16 -------------------
__global__ void k_vecdot(const u16* __restrict__ vp, const float* __restrict__ x,
                         float* __restrict__ vec_dot, u16* __restrict__ hcat) {
    int i = blockIdx.x * 256 + threadIdx.x;  // N*H
    int n = i >> 8, c = i & 255;
    const u16* p = vp + (size_t)n * 1536;
    float dsum = 0.f, qsum = 0.f;
#pragma unroll
    for (int k = 0; k < 3; ++k) {
        float v1 = b2f(p[k * 512 + c]);
        float v2 = b2f(p[k * 512 + 256 + c]);
        dsum += v1 * v2;
        qsum += v2 * v2;
    }
    vec_dot[i] = dsum * kInvSqrtH;
    hcat[(size_t)n * 512 + c] = f2b(x[i]);
    hcat[(size_t)n * 512 + 256 + c] = f2b(sqrtf(qsum + 1e-8f));
}

// ---------------- update epilogue + fused LayerNorm for next layer ----------------
__global__ void k_update_out(const u16* __restrict__ hout, const float* __restrict__ vec_dot,
                             const u16* __restrict__ vp, float* __restrict__ x,
                             const float* __restrict__ vecM, float* __restrict__ vfin,
                             u16* __restrict__ vb,
                             const float* __restrict__ lnw, const float* __restrict__ lnb,
                             u16* __restrict__ xout) {
    int n = blockIdx.x, t = threadIdx.x;
    size_t i = (size_t)n * 256 + t;
    float xv1 = b2f(hout[(size_t)n * 768 + t]);
    float xv2 = b2f(hout[(size_t)n * 768 + 256 + t]);
    float xv3 = b2f(hout[(size_t)n * 768 + 512 + t]);
    float dxv = (xv1 + xv2 * vec_dot[i]) * kInvSqrt2;
    float nx = (x[i] + dxv) * kInvSqrt2;
    x[i] = nx;
#pragma unroll
    for (int k = 0; k < 3; ++k) {
        size_t idx = (size_t)n * 768 + k * 256 + t;
        float nv = vecM[idx] + xv3 * b2f(vp[(size_t)n * 1536 + k * 512 + t]);
        vfin[idx] = nv;
        vb[idx] = f2b(nv);
    }
    if (lnw) {
        float s = nx, q = nx * nx;
#pragma unroll
        for (int m = 32; m >= 1; m >>= 1) {
            s += __shfl_xor(s, m, 64);
            q += __shfl_xor(q, m, 64);
        }
        __shared__ float s_sum[4], s_sq[4];
        int wid = t >> 6;
        if ((t & 63) == 0) { s_sum[wid] = s; s_sq[wid] = q; }
        __syncthreads();
        float S = s_sum[0] + s_sum[1] + s_sum[2] + s_sum[3];
        float Q = s_sq[0] + s_sq[1] + s_sq[2] + s_sq[3];
        float mu = S * (1.0f / HH);
        float var = Q * (1.0f / HH) - mu * mu;
        float rs = rsqrtf(var + 1e-5f);
        xout[i] = f2b((nx - mu) * rs * lnw[t] + lnb[t]);
    } else {
        xout[i] = f2b(nx);
    }
}

// ---------------- energy reduce ----------------
__global__ void k_energy2(const float* __restrict__ h, const float* __restrict__ w2,
                          const float* __restrict__ b2, const int* __restrict__ batch,
                          float* __restrict__ out) {
    __shared__ float g[NGG];
    int t = threadIdx.x;
    if (t < NGG) g[t] = 0.f;
    __syncthreads();
    int a = blockIdx.x * 256 + t;
    const float4* hr = (const float4*)(h + (size_t)a * 128);
    const float4* w4 = (const float4*)w2;
    float acc = 0.f;
#pragma unroll 8
    for (int i = 0; i < 32; ++i) {
        float4 hv = hr[i], wv = w4[i];
        acc += hv.x * wv.x + hv.y * wv.y + hv.z * wv.z + hv.w * wv.w;
    }
    acc += b2[0];
    atomicAdd(&g[batch[a]], acc);
    __syncthreads();
    if (t < NGG && g[t] != 0.f) atomicAdd(&out[t], g[t]);
}

extern "C" void kernel_launch(void* const* d_in, const int* in_sizes, int n_in,
                              void* d_out, int out_size, void* d_ws, size_t ws_size,
                              hipStream_t stream) {
    const float* pos      = (const float*)d_in[0];
    const float* atom_emb = (const float*)d_in[1];
    const float* ln_w     = (const float*)d_in[2];
    const float* ln_b     = (const float*)d_in[3];
    const float* xp_w1    = (const float*)d_in[4];
    const float* xp_b1    = (const float*)d_in[5];
    const float* xp_w2    = (const float*)d_in[6];
    const float* xp_b2    = (const float*)d_in[7];
    const float* rbf_w    = (const float*)d_in[8];
    const float* rbf_b    = (const float*)d_in[9];
    const float* vec_w    = (const float*)d_in[10];
    const float* xv_w1    = (const float*)d_in[11];
    const float* xv_b1    = (const float*)d_in[12];
    const float* xv_w2    = (const float*)d_in[13];
    const float* xv_b2    = (const float*)d_in[14];
    const float* oe_w1    = (const float*)d_in[15];
    const float* oe_b1    = (const float*)d_in[16];
    const float* oe_w2    = (const float*)d_in[17];
    const float* oe_b2    = (const float*)d_in[18];
    const int*   z        = (const int*)d_in[19];
    const int*   ei       = (const int*)d_in[20];
    const int*   batch    = (const int*)d_in[21];
    float* out = (float*)d_out;

    char* ws = (char*)d_ws;
    size_t off = 0;
    auto alloc = [&](size_t b) {
        void* p = ws + off;
        off = (off + b + 255) & ~(size_t)255;
        return p;
    };
    float*  x      = (float*)alloc((size_t)NN * HH * 4);       //   8 MB
    float*  vecA   = (float*)alloc((size_t)NN * 768 * 4);      //  24 MB  \ adjacent:
    u16*    vb     = (u16*)alloc((size_t)NN * 768 * 2);        //  12 MB  / joint zero
    float*  vecM   = (float*)alloc((size_t)NN * 768 * 4);      //  24 MB
    u16*    xlnb   = (u16*)alloc((size_t)NN * HH * 2);         //   4 MB (alias xb)
    u16*    t1b    = (u16*)alloc((size_t)NN * HH * 2);         //   4 MB (alias h1b)
    u16*    xhb    = (u16*)alloc((size_t)NN * 768 * 2);        //  12 MB (alias hcatb)
    float*  vdot   = (float*)alloc((size_t)NN * HH * 4);       //   8 MB (alias heng)
    u16*    vpb    = (u16*)alloc((size_t)NN * 1536 * 2);       //  24 MB
    u16*    houtb  = (u16*)alloc((size_t)NN * 768 * 2);        //  12 MB
    float*  ev     = (float*)alloc((size_t)EE * 4 * 4);        //   2 MB
    int*    deg    = (int*)alloc((size_t)NN * 4);
    int*    row_ptr= (int*)alloc((size_t)(NN + 1) * 4);
    int*    fill   = (int*)alloc((size_t)NN * 4);
    int*    srcp   = (int*)alloc((size_t)EE * 4);
    float4* evp    = (float4*)alloc((size_t)EE * 16);          //   2 MB
    int*    k0tab  = (int*)alloc((size_t)EE * 4);              // 0.5 MB
    float*  gtab   = (float*)alloc((size_t)EE * 8 * 4);        //   4 MB
    u16* xp_w1T   = (u16*)alloc((size_t)3 * 256 * 256 * 2);
    u16* xp_w2T   = (u16*)alloc((size_t)3 * 768 * 256 * 2);
    u16* rbf_wKb  = (u16*)alloc((size_t)3 * 128 * 768 * 2);    // k-major bf16 cast
    u16* vec_wT   = (u16*)alloc((size_t)3 * 512 * 256 * 2);
    u16* xv_w1T   = (u16*)alloc((size_t)3 * 256 * 512 * 2);
    u16* xv_w2T   = (u16*)alloc((size_t)3 * 768 * 256 * 2);
    u16* oe_w1T   = (u16*)alloc((size_t)128 * 256 * 2);
    (void)ws_size;

    u16*   h1b   = t1b;
    u16*   hcatb = xhb;
    float* heng  = vdot;
    u16*   xb    = xlnb;

    // ---- setup ----
    k_wt_all<<<2432, 256, 0, stream>>>(xp_w1, xp_w2, rbf_w, vec_w, xv_w1, xv_w2, oe_w1,
                                       xp_w1T, xp_w2T, rbf_wKb, vec_wT, xv_w1T, xv_w2T, oe_w1T);
    k_zero<<<(36 * 1024 * 1024 / 16 + 255) / 256, 256, 0, stream>>>(vecA, 36 * 1024 * 1024 / 16);
    k_zero<<<8, 256, 0, stream>>>((float*)deg, NN / 4);
    k_init_ln<<<NN, 256, 0, stream>>>(atom_emb, z, ln_w, ln_b, x, xlnb);
    k_edge_geom<<<EE / 256, 256, 0, stream>>>(pos, ei, ev);
    k_hist<<<EE / 256, 256, 0, stream>>>(ei, deg);
    k_scan<<<1, 256, 0, stream>>>(deg, row_ptr, fill);
    k_scatter<<<EE / 256, 256, 0, stream>>>(ei, ev, fill, srcp, evp, k0tab, gtab);

    for (int l = 0; l < LL; ++l) {
        // ---- PaiNNMessage ----
        k_gemm<0, 1, 1><<<dim3(2, NN / 128), 256, 0, stream>>>(
            xlnb, xp_w1T + (size_t)l * 256 * 256, xp_b1 + l * HH, t1b, NN, 256, 256);
        k_gemm<0, 1, 0><<<dim3(6, NN / 128), 256, 0, stream>>>(
            t1b, xp_w2T + (size_t)l * 768 * 256, xp_b2 + l * 768, xhb, NN, 256, 768);
        k_msg<<<NN / DPB, 256, 0, stream>>>(
            xhb, vb, srcp, evp, row_ptr, k0tab, gtab,
            rbf_wKb + (size_t)l * 128 * 768, rbf_b + l * 768, x, vecA, vecM);

        // ---- PaiNNUpdate ----
        k_gemm<1, 1, 0><<<dim3(4, 3 * NN / 128), 256, 0, stream>>>(
            vecM, vec_wT + (size_t)l * 512 * 256, nullptr, vpb, 3 * NN, 256, 512);
        k_vecdot<<<NN, 256, 0, stream>>>(vpb, x, vdot, hcatb);
        k_gemm<0, 1, 1><<<dim3(2, NN / 128), 256, 0, stream>>>(
            hcatb, xv_w1T + (size_t)l * 256 * 512, xv_b1 + l * HH, h1b, NN, 512, 256);
        k_gemm<0, 1, 0><<<dim3(6, NN / 128), 256, 0, stream>>>(
            h1b, xv_w2T + (size_t)l * 768 * 256, xv_b2 + l * 768, houtb, NN, 256, 768);
        bool last = (l == LL - 1);
        k_update_out<<<NN, 256, 0, stream>>>(
            houtb, vdot, vpb, x, vecM, vecA, vb,
            last ? nullptr : ln_w + (l + 1) * HH,
            last ? nullptr : ln_b + (l + 1) * HH, xlnb);
    }

    // ---- energy head ----
    k_gemm<0, 0, 1><<<dim3(1, NN / 128), 256, 0, stream>>>(
        xb, oe_w1T, oe_b1, heng, NN, 256, 128);
    k_zero<<<1, 256, 0, stream>>>(out, NGG / 4);
    k_energy2<<<32, 256, 0, stream>>>(heng, oe_w2, oe_b2, batch, out);
}

// Round 13
// 821.667 us; speedup vs baseline: 1.3792x; 1.2263x over previous
//
#include <hip/hip_runtime.h>
#include <hip/hip_bf16.h>
#include <math.h>

#define NN 8192
#define EE 131072
#define HH 256
#define LL 3
#define RR 128
#define NGG 64
#define MSG_WAVES 16         // waves per k_msg block (1024 threads)

typedef __attribute__((ext_vector_type(8))) short bf16x8;
typedef __attribute__((ext_vector_type(4))) float f32x4;
typedef unsigned short u16;

union U4 { ushort4 v; unsigned short a[4]; };
union U8 { uint4 v; unsigned short a[8]; };

__device__ __forceinline__ float silu(float v) { return v / (1.0f + expf(-v)); }
__device__ __forceinline__ float b2f(unsigned short u) { return __uint_as_float(((unsigned)u) << 16); }
__device__ __forceinline__ unsigned short f2b(float f) {
    unsigned u = __float_as_uint(f);
    u += 0x7fff + ((u >> 16) & 1);
    return (unsigned short)(u >> 16);
}

constexpr float kInvSqrt2 = 0.70710678118654752440f;
constexpr float kInvSqrt3 = 0.57735026918962576451f;
constexpr float kInvSqrtH = 0.0625f; // 1/sqrt(256)

// ---------------- utility ----------------
__global__ void k_zero(float* __restrict__ p, int n4) {
    int i = blockIdx.x * 256 + threadIdx.x;
    if (i < n4) ((float4*)p)[i] = make_float4(0.f, 0.f, 0.f, 0.f);
}

// ---------------- ALL weight prep in one launch ----------------
// transpose in[K,N] fp32 -> out[N,K] bf16, except rbf_w: straight cast (k-major kept)
__global__ __launch_bounds__(256) void k_wt_all(
    const float* __restrict__ xp_w1, const float* __restrict__ xp_w2,
    const float* __restrict__ rbf_w, const float* __restrict__ vec_w,
    const float* __restrict__ xv_w1, const float* __restrict__ xv_w2,
    const float* __restrict__ oe_w1,
    u16* __restrict__ xp_w1T, u16* __restrict__ xp_w2T, u16* __restrict__ rbf_wKb,
    u16* __restrict__ vec_wT, u16* __restrict__ xv_w1T, u16* __restrict__ xv_w2T,
    u16* __restrict__ oe_w1T) {
    int bid = blockIdx.x;
    const float* src; u16* dst; int K, N, t, cast = 0;
    if (bid < 2400) {
        int l = bid / 800, r = bid % 800;
        if (r < 64)       { src = xp_w1 + (size_t)l * 65536;  dst = xp_w1T + (size_t)l * 65536;  K = 256; N = 256; t = r; }
        else if (r < 256) { src = xp_w2 + (size_t)l * 196608; dst = xp_w2T + (size_t)l * 196608; K = 256; N = 768; t = r - 64; }
        else if (r < 352) { src = rbf_w + (size_t)l * 98304;  dst = rbf_wKb + (size_t)l * 98304; K = 128; N = 768; t = r - 256; cast = 1; }
        else if (r < 480) { src = vec_w + (size_t)l * 131072; dst = vec_wT + (size_t)l * 131072; K = 256; N = 512; t = r - 352; }
        else if (r < 608) { src = xv_w1 + (size_t)l * 131072; dst = xv_w1T + (size_t)l * 131072; K = 512; N = 256; t = r - 480; }
        else              { src = xv_w2 + (size_t)l * 196608; dst = xv_w2T + (size_t)l * 196608; K = 256; N = 768; t = r - 608; }
    } else {
        src = oe_w1; dst = oe_w1T; K = 256; N = 128; t = bid - 2400;
    }
    int nx = N >> 5;
    int bn = (t % nx) * 32, bk = (t / nx) * 32;
    int tx = threadIdx.x & 31, ty = threadIdx.x >> 5;   // 32 x 8
    if (cast) {
#pragma unroll
        for (int i = 0; i < 32; i += 8)
            dst[(size_t)(bk + ty + i) * N + bn + tx] = f2b(src[(size_t)(bk + ty + i) * N + bn + tx]);
        return;
    }
    __shared__ float tile[32][33];
#pragma unroll
    for (int i = 0; i < 32; i += 8)
        tile[ty + i][tx] = src[(size_t)(bk + ty + i) * N + bn + tx];
    __syncthreads();
#pragma unroll
    for (int i = 0; i < 32; i += 8)
        dst[(size_t)(bn + ty + i) * K + bk + tx] = f2b(tile[tx][ty + i]);
}

// ---------------- init: x = atom_emb[z], + LayerNorm(ln[0]) -> xlnb ----------------
__global__ void k_init_ln(const float* __restrict__ emb, const int* __restrict__ z,
                          const float* __restrict__ w, const float* __restrict__ b,
                          float* __restrict__ x, u16* __restrict__ xlnb) {
    int n = blockIdx.x, t = threadIdx.x;
    float v = emb[z[n] * HH + t];
    x[(size_t)n * HH + t] = v;
    float s = v, q = v * v;
#pragma unroll
    for (int m = 32; m >= 1; m >>= 1) {
        s += __shfl_xor(s, m, 64);
        q += __shfl_xor(q, m, 64);
    }
    __shared__ float s_sum[4], s_sq[4];
    int wid = t >> 6;
    if ((t & 63) == 0) { s_sum[wid] = s; s_sq[wid] = q; }
    __syncthreads();
    float S = s_sum[0] + s_sum[1] + s_sum[2] + s_sum[3];
    float Q = s_sq[0] + s_sq[1] + s_sq[2] + s_sq[3];
    float mu = S * (1.0f / HH);
    float var = Q * (1.0f / HH) - mu * mu;
    float rs = rsqrtf(var + 1e-5f);
    xlnb[(size_t)n * HH + t] = f2b((v - mu) * rs * w[t] + b[t]);
}

// ---------------- edge geometry ----------------
__global__ void k_edge_geom(const float* __restrict__ pos, const int* __restrict__ ei,
                            float* __restrict__ ev /*[E,4]*/) {
    int e = blockIdx.x * 256 + threadIdx.x;
    if (e >= EE) return;
    int s = ei[e], d = ei[EE + e];
    float rx = pos[s * 3 + 0] - pos[d * 3 + 0];
    float ry = pos[s * 3 + 1] - pos[d * 3 + 1];
    float rz = pos[s * 3 + 2] - pos[d * 3 + 2];
    float dist = sqrtf(rx * rx + ry * ry + rz * rz);
    float inv = 1.0f / dist;
    ((float4*)ev)[e] = make_float4(rx * inv, ry * inv, rz * inv, dist);
}

// ---------------- CSR build ----------------
__global__ void k_hist(const int* __restrict__ ei, int* __restrict__ deg) {
    int e = blockIdx.x * 256 + threadIdx.x;
    if (e < EE) atomicAdd(&deg[ei[EE + e]], 1);
}
__global__ void k_scan(const int* __restrict__ deg, int* __restrict__ row_ptr,
                       int* __restrict__ fill) {
    __shared__ int buf[256];
    __shared__ int carry_s;
    int t = threadIdx.x;
    if (t == 0) carry_s = 0;
    __syncthreads();
    for (int r = 0; r < NN; r += 256) {
        int v = deg[r + t];
        buf[t] = v;
        __syncthreads();
        for (int ofs = 1; ofs < 256; ofs <<= 1) {
            int add = (t >= ofs) ? buf[t - ofs] : 0;
            __syncthreads();
            buf[t] += add;
            __syncthreads();
        }
        int excl = buf[t] - v;
        int carry = carry_s;
        row_ptr[r + t] = carry + excl;
        fill[r + t] = carry + excl;
        __syncthreads();
        if (t == 255) carry_s = carry + buf[t];
        __syncthreads();
    }
    if (t == 0) row_ptr[NN] = carry_s;
}
// scatter + fused per-edge gaussian window table (8 rows, k0 clamp [0,120])
__global__ void k_scatter(const int* __restrict__ ei, const float* __restrict__ ev,
                          int* __restrict__ fill, int* __restrict__ srcp,
                          float4* __restrict__ evp, int* __restrict__ k0tab,
                          float* __restrict__ gtab) {
    int e = blockIdx.x * 256 + threadIdx.x;
    if (e >= EE) return;
    int d = ei[EE + e];
    int pos = atomicAdd(&fill[d], 1);
    float4 e4 = ((const float4*)ev)[e];
    srcp[pos] = ei[e];
    evp[pos] = e4;
    const float step = 12.0f / 127.0f;
    const float coeff = -0.5f / (step * step);
    float dist = e4.w;
    int k0 = (int)floorf(dist / step) - 3;
    k0 = k0 < 0 ? 0 : (k0 > 120 ? 120 : k0);
    float g[8];
#pragma unroll
    for (int k = 0; k < 8; ++k) {
        float t = dist - (k0 + k) * step;
        g[k] = expf(coeff * t * t);
    }
    k0tab[pos] = k0;
    ((float4*)gtab)[pos * 2 + 0] = make_float4(g[0], g[1], g[2], g[3]);
    ((float4*)gtab)[pos * 2 + 1] = make_float4(g[4], g[5], g[6], g[7]);
}

// ---------------- bf16 MFMA GEMM: C = act(A[M,K] @ BT[N,K]^T + bias) ----------------
template <int AF32, int OUT_BF16, int ACT>
__global__ __launch_bounds__(256) void k_gemm(
    const void* __restrict__ Av, const u16* __restrict__ BT,
    const float* __restrict__ bias, void* __restrict__ C, int M, int K, int N) {
    __shared__ uint4 As4[512];
    __shared__ uint4 Bs4[512];
    u16* As = (u16*)As4;
    u16* Bs = (u16*)Bs4;
    int tid = threadIdx.x;
    int wave = tid >> 6, lane = tid & 63;
    int bm = blockIdx.y * 128, bn = blockIdx.x * 128;
    int wm = (wave >> 1) * 64, wn = (wave & 1) * 64;
    int lm = lane & 15;
    int kg = lane >> 4;
    f32x4 acc[4][4] = {};

    for (int k0 = 0; k0 < K; k0 += 32) {
#pragma unroll
        for (int it = 0; it < 2; ++it) {
            int idx = it * 256 + tid;
            int r = idx >> 2, seg = idx & 3;
            if (AF32) {
                const float* Af = (const float*)Av;
                float4 fa = *(const float4*)&Af[(size_t)(bm + r) * K + k0 + seg * 8];
                float4 fb = *(const float4*)&Af[(size_t)(bm + r) * K + k0 + seg * 8 + 4];
                U8 u;
                u.a[0] = f2b(fa.x); u.a[1] = f2b(fa.y); u.a[2] = f2b(fa.z); u.a[3] = f2b(fa.w);
                u.a[4] = f2b(fb.x); u.a[5] = f2b(fb.y); u.a[6] = f2b(fb.z); u.a[7] = f2b(fb.w);
                As4[idx] = u.v;
            } else {
                const u16* A = (const u16*)Av;
                As4[idx] = *(const uint4*)&A[(size_t)(bm + r) * K + k0 + seg * 8];
            }
            Bs4[idx] = *(const uint4*)&BT[(size_t)(bn + r) * K + k0 + seg * 8];
        }
        __syncthreads();
        bf16x8 af[4], bfr[4];
#pragma unroll
        for (int i = 0; i < 4; ++i)
            af[i] = *(const bf16x8*)&As[(wm + i * 16 + lm) * 32 + kg * 8];
#pragma unroll
        for (int j = 0; j < 4; ++j)
            bfr[j] = *(const bf16x8*)&Bs[(wn + j * 16 + lm) * 32 + kg * 8];
#pragma unroll
        for (int i = 0; i < 4; ++i)
#pragma unroll
            for (int j = 0; j < 4; ++j)
                acc[i][j] = __builtin_amdgcn_mfma_f32_16x16x32_bf16(af[i], bfr[j], acc[i][j], 0, 0, 0);
        __syncthreads();
    }

#pragma unroll
    for (int j = 0; j < 4; ++j) {
        int col = bn + wn + j * 16 + lm;
        float bv = bias ? bias[col] : 0.f;
#pragma unroll
        for (int i = 0; i < 4; ++i) {
            int row0 = bm + wm + i * 16 + kg * 4;
#pragma unroll
            for (int r = 0; r < 4; ++r) {
                float v = acc[i][j][r] + bv;
                if (ACT) v = silu(v);
                if (OUT_BF16)
                    ((u16*)C)[(size_t)(row0 + r) * N + col] = f2b(v);
                else
                    ((float*)C)[(size_t)(row0 + r) * N + col] = v;
            }
        }
    }
}

// ---------------- fused message pass v8: 64KB panel shared by 16 waves -------------
// 1024-thread blocks: LDS per-block is amortized over 4x more waves than R8 ->
// 16-20 waves/CU instead of 8, hiding gather latency. One dst per wave.
__global__ __launch_bounds__(1024) void k_msg(
    const u16* __restrict__ xhb, const u16* __restrict__ vinb,
    const int* __restrict__ srcp, const float4* __restrict__ evp,
    const int* __restrict__ row_ptr, const int* __restrict__ k0tab,
    const float* __restrict__ gtab, const u16* __restrict__ WK /*[128][768] bf16*/,
    const float* __restrict__ rbias, float* __restrict__ x,
    const float* __restrict__ vin, float* __restrict__ vecM) {
    __shared__ u16 Wp[128 * 256];   // 64 KB panel
    int tid = threadIdx.x;
    int wave = tid >> 6, lane = tid & 63;
    int c0 = lane * 4;
    int d = blockIdx.x * MSG_WAVES + wave;   // one dst per wave
    int E0 = row_ptr[d], E1 = row_ptr[d + 1];
    float accv[3][4] = {};          // persists across panels 1,2

#pragma unroll
    for (int p = 0; p < 3; ++p) {
        __syncthreads();
#pragma unroll
        for (int it = 0; it < 4; ++it) {        // cooperative 64KB panel load
            int idx = it * 1024 + tid;          // 4096 uint4s
            int row = idx >> 5;
            int col8 = (idx & 31) * 8;
            *(uint4*)&Wp[row * 256 + col8] =
                *(const uint4*)&WK[(size_t)row * 768 + p * 256 + col8];
        }
        __syncthreads();
        float4 bb = ((const float4*)(rbias + p * 256))[lane];
        float bias4[4] = {bb.x, bb.y, bb.z, bb.w};
        float accx[4] = {};
        for (int j = E0; j < E1; ++j) {
            int s = srcp[j];
            int kj = k0tab[j];
            float4 ga = ((const float4*)gtab)[(size_t)j * 2 + 0];
            float4 gb = ((const float4*)gtab)[(size_t)j * 2 + 1];
            float g[8] = {ga.x, ga.y, ga.z, ga.w, gb.x, gb.y, gb.z, gb.w};
            float rr[4] = {bias4[0], bias4[1], bias4[2], bias4[3]};
#pragma unroll
            for (int k = 0; k < 8; ++k) {
                U4 w;
                w.v = *(const ushort4*)&Wp[(kj + k) * 256 + c0];
#pragma unroll
                for (int c = 0; c < 4; ++c) rr[c] += g[k] * b2f(w.a[c]);
            }
            if (p == 0) {
                U4 X; X.v = *(const ushort4*)(xhb + (size_t)s * 768 + c0);
#pragma unroll
                for (int c = 0; c < 4; ++c) accx[c] += b2f(X.a[c]) * rr[c];
            } else if (p == 1) {
                U4 X, V0, V1, V2;
                X.v = *(const ushort4*)(xhb + (size_t)s * 768 + 256 + c0);
                V0.v = *(const ushort4*)(vinb + (size_t)s * 768 + c0);
                V1.v = *(const ushort4*)(vinb + (size_t)s * 768 + 256 + c0);
                V2.v = *(const ushort4*)(vinb + (size_t)s * 768 + 512 + c0);
#pragma unroll
                for (int c = 0; c < 4; ++c) {
                    float m1 = b2f(X.a[c]) * rr[c] * kInvSqrt3;
                    accv[0][c] += b2f(V0.a[c]) * m1;
                    accv[1][c] += b2f(V1.a[c]) * m1;
                    accv[2][c] += b2f(V2.a[c]) * m1;
                }
            } else {
                U4 X; X.v = *(const ushort4*)(xhb + (size_t)s * 768 + 512 + c0);
                float4 ev4 = evp[j];
#pragma unroll
                for (int c = 0; c < 4; ++c) {
                    float m2 = b2f(X.a[c]) * rr[c];
                    accv[0][c] += m2 * ev4.x;
                    accv[1][c] += m2 * ev4.y;
                    accv[2][c] += m2 * ev4.z;
                }
            }
        }
        if (p == 0) {
            size_t xi = (size_t)d * 256 + c0;
            float4 xv = *(const float4*)&x[xi];
            xv.x = (xv.x + accx[0]) * kInvSqrt2;
            xv.y = (xv.y + accx[1]) * kInvSqrt2;
            xv.z = (xv.z + accx[2]) * kInvSqrt2;
            xv.w = (xv.w + accx[3]) * kInvSqrt2;
            *(float4*)&x[xi] = xv;
        }
    }
    // epilogue: vecM = vin + dvec * invSqrtH
#pragma unroll
    for (int k = 0; k < 3; ++k) {
        size_t idx = (size_t)d * 768 + k * 256 + c0;
        float4 vv = *(const float4*)&vin[idx];
        vv.x += accv[k][0] * kInvSqrtH;
        vv.y += accv[k][1] * kInvSqrtH;
        vv.z += accv[k][2] * kInvSqrtH;
        vv.w += accv[k][3] * kInvSqrtH;
        *(float4*)&vecM[idx] = vv;
    }
}

// ---------------- vec_dot + hcat(bf16) = [x, vnorm]; vp in bf16 -------------------
__global__ void k_vecdot(const u16* __restrict__ vp, const float* __restrict__ x,
                         float* __restrict__ vec_dot, u16* __restrict__ hcat) {
    int i = blockIdx.x * 256 + threadIdx.x;  // N*H
    int n = i >> 8, c = i & 255;
    const u16* p = vp + (size_t)n * 1536;
    float dsum = 0.f, qsum = 0.f;
#pragma unroll
    for (int k = 0; k < 3; ++k) {
        float v1 = b2f(p[k * 512 + c]);
        float v2 = b2f(p[k * 512 + 256 + c]);
        dsum += v1 * v2;
        qsum += v2 * v2;
    }
    vec_dot[i] = dsum * kInvSqrtH;
    hcat[(size_t)n * 512 + c] = f2b(x[i]);
    hcat[(size_t)n * 512 + 256 + c] = f2b(sqrtf(qsum + 1e-8f));
}

// ---------------- update epilogue + fused LayerNorm for next layer ----------------
__global__ void k_update_out(const u16* __restrict__ hout, const float* __restrict__ vec_dot,
                             const u16* __restrict__ vp, float* __restrict__ x,
                             const float* __restrict__ vecM, float* __restrict__ vfin,
                             u16* __restrict__ vb,
                             const float* __restrict__ lnw, const float* __restrict__ lnb,
                             u16* __restrict__ xout) {
    int n = blockIdx.x, t = threadIdx.x;
    size_t i = (size_t)n * 256 + t;
    float xv1 = b2f(hout[(size_t)n * 768 + t]);
    float xv2 = b2f(hout[(size_t)n * 768 + 256 + t]);
    float xv3 = b2f(hout[(size_t)n * 768 + 512 + t]);
    float dxv = (xv1 + xv2 * vec_dot[i]) * kInvSqrt2;
    float nx = (x[i] + dxv) * kInvSqrt2;
    x[i] = nx;
#pragma unroll
    for (int k = 0; k < 3; ++k) {
        size_t idx = (size_t)n * 768 + k * 256 + t;
        float nv = vecM[idx] + xv3 * b2f(vp[(size_t)n * 1536 + k * 512 + t]);
        vfin[idx] = nv;
        vb[idx] = f2b(nv);
    }
    if (lnw) {
        float s = nx, q = nx * nx;
#pragma unroll
        for (int m = 32; m >= 1; m >>= 1) {
            s += __shfl_xor(s, m, 64);
            q += __shfl_xor(q, m, 64);
        }
        __shared__ float s_sum[4], s_sq[4];
        int wid = t >> 6;
        if ((t & 63) == 0) { s_sum[wid] = s; s_sq[wid] = q; }
        __syncthreads();
        float S = s_sum[0] + s_sum[1] + s_sum[2] + s_sum[3];
        float Q = s_sq[0] + s_sq[1] + s_sq[2] + s_sq[3];
        float mu = S * (1.0f / HH);
        float var = Q * (1.0f / HH) - mu * mu;
        float rs = rsqrtf(var + 1e-5f);
        xout[i] = f2b((nx - mu) * rs * lnw[t] + lnb[t]);
    } else {
        xout[i] = f2b(nx);
    }
}

// ---------------- energy reduce ----------------
__global__ void k_energy2(const float* __restrict__ h, const float* __restrict__ w2,
                          const float* __restrict__ b2, const int* __restrict__ batch,
                          float* __restrict__ out) {
    __shared__ float g[NGG];
    int t = threadIdx.x;
    if (t < NGG) g[t] = 0.f;
    __syncthreads();
    int a = blockIdx.x * 256 + t;
    const float4* hr = (const float4*)(h + (size_t)a * 128);
    const float4* w4 = (const float4*)w2;
    float acc = 0.f;
#pragma unroll 8
    for (int i = 0; i < 32; ++i) {
        float4 hv = hr[i], wv = w4[i];
        acc += hv.x * wv.x + hv.y * wv.y + hv.z * wv.z + hv.w * wv.w;
    }
    acc += b2[0];
    atomicAdd(&g[batch[a]], acc);
    __syncthreads();
    if (t < NGG && g[t] != 0.f) atomicAdd(&out[t], g[t]);
}

extern "C" void kernel_launch(void* const* d_in, const int* in_sizes, int n_in,
                              void* d_out, int out_size, void* d_ws, size_t ws_size,
                              hipStream_t stream) {
    const float* pos      = (const float*)d_in[0];
    const float* atom_emb = (const float*)d_in[1];
    const float* ln_w     = (const float*)d_in[2];
    const float* ln_b     = (const float*)d_in[3];
    const float* xp_w1    = (const float*)d_in[4];
    const float* xp_b1    = (const float*)d_in[5];
    const float* xp_w2    = (const float*)d_in[6];
    const float* xp_b2    = (const float*)d_in[7];
    const float* rbf_w    = (const float*)d_in[8];
    const float* rbf_b    = (const float*)d_in[9];
    const float* vec_w    = (const float*)d_in[10];
    const float* xv_w1    = (const float*)d_in[11];
    const float* xv_b1    = (const float*)d_in[12];
    const float* xv_w2    = (const float*)d_in[13];
    const float* xv_b2    = (const float*)d_in[14];
    const float* oe_w1    = (const float*)d_in[15];
    const float* oe_b1    = (const float*)d_in[16];
    const float* oe_w2    = (const float*)d_in[17];
    const float* oe_b2    = (const float*)d_in[18];
    const int*   z        = (const int*)d_in[19];
    const int*   ei       = (const int*)d_in[20];
    const int*   batch    = (const int*)d_in[21];
    float* out = (float*)d_out;

    char* ws = (char*)d_ws;
    size_t off = 0;
    auto alloc = [&](size_t b) {
        void* p = ws + off;
        off = (off + b + 255) & ~(size_t)255;
        return p;
    };
    float*  x      = (float*)alloc((size_t)NN * HH * 4);       //   8 MB
    float*  vecA   = (float*)alloc((size_t)NN * 768 * 4);      //  24 MB  \ adjacent:
    u16*    vb     = (u16*)alloc((size_t)NN * 768 * 2);        //  12 MB  / joint zero
    float*  vecM   = (float*)alloc((size_t)NN * 768 * 4);      //  24 MB
    u16*    xlnb   = (u16*)alloc((size_t)NN * HH * 2);         //   4 MB (alias xb)
    u16*    t1b    = (u16*)alloc((size_t)NN * HH * 2);         //   4 MB (alias h1b)
    u16*    xhb    = (u16*)alloc((size_t)NN * 768 * 2);        //  12 MB (alias hcatb)
    float*  vdot   = (float*)alloc((size_t)NN * HH * 4);       //   8 MB (alias heng)
    u16*    vpb    = (u16*)alloc((size_t)NN * 1536 * 2);       //  24 MB
    u16*    houtb  = (u16*)alloc((size_t)NN * 768 * 2);        //  12 MB
    float*  ev     = (float*)alloc((size_t)EE * 4 * 4);        //   2 MB
    int*    deg    = (int*)alloc((size_t)NN * 4);
    int*    row_ptr= (int*)alloc((size_t)(NN + 1) * 4);
    int*    fill   = (int*)alloc((size_t)NN * 4);
    int*    srcp   = (int*)alloc((size_t)EE * 4);
    float4* evp    = (float4*)alloc((size_t)EE * 16);          //   2 MB
    int*    k0tab  = (int*)alloc((size_t)EE * 4);              // 0.5 MB
    float*  gtab   = (float*)alloc((size_t)EE * 8 * 4);        //   4 MB
    u16* xp_w1T   = (u16*)alloc((size_t)3 * 256 * 256 * 2);
    u16* xp_w2T   = (u16*)alloc((size_t)3 * 768 * 256 * 2);
    u16* rbf_wKb  = (u16*)alloc((size_t)3 * 128 * 768 * 2);    // k-major bf16 cast
    u16* vec_wT   = (u16*)alloc((size_t)3 * 512 * 256 * 2);
    u16* xv_w1T   = (u16*)alloc((size_t)3 * 256 * 512 * 2);
    u16* xv_w2T   = (u16*)alloc((size_t)3 * 768 * 256 * 2);
    u16* oe_w1T   = (u16*)alloc((size_t)128 * 256 * 2);
    (void)ws_size;

    u16*   h1b   = t1b;
    u16*   hcatb = xhb;
    float* heng  = vdot;
    u16*   xb    = xlnb;

    // ---- setup ----
    k_wt_all<<<2432, 256, 0, stream>>>(xp_w1, xp_w2, rbf_w, vec_w, xv_w1, xv_w2, oe_w1,
                                       xp_w1T, xp_w2T, rbf_wKb, vec_wT, xv_w1T, xv_w2T, oe_w1T);
    k_zero<<<(36 * 1024 * 1024 / 16 + 255) / 256, 256, 0, stream>>>(vecA, 36 * 1024 * 1024 / 16);
    k_zero<<<8, 256, 0, stream>>>((float*)deg, NN / 4);
    k_init_ln<<<NN, 256, 0, stream>>>(atom_emb, z, ln_w, ln_b, x, xlnb);
    k_edge_geom<<<EE / 256, 256, 0, stream>>>(pos, ei, ev);
    k_hist<<<EE / 256, 256, 0, stream>>>(ei, deg);
    k_scan<<<1, 256, 0, stream>>>(deg, row_ptr, fill);
    k_scatter<<<EE / 256, 256, 0, stream>>>(ei, ev, fill, srcp, evp, k0tab, gtab);

    for (int l = 0; l < LL; ++l) {
        // ---- PaiNNMessage ----
        k_gemm<0, 1, 1><<<dim3(2, NN / 128), 256, 0, stream>>>(
            xlnb, xp_w1T + (size_t)l * 256 * 256, xp_b1 + l * HH, t1b, NN, 256, 256);
        k_gemm<0, 1, 0><<<dim3(6, NN / 128), 256, 0, stream>>>(
            t1b, xp_w2T + (size_t)l * 768 * 256, xp_b2 + l * 768, xhb, NN, 256, 768);
        k_msg<<<NN / MSG_WAVES, 1024, 0, stream>>>(
            xhb, vb, srcp, evp, row_ptr, k0tab, gtab,
            rbf_wKb + (size_t)l * 128 * 768, rbf_b + l * 768, x, vecA, vecM);

        // ---- PaiNNUpdate ----
        k_gemm<1, 1, 0><<<dim3(4, 3 * NN / 128), 256, 0, stream>>>(
            vecM, vec_wT + (size_t)l * 512 * 256, nullptr, vpb, 3 * NN, 256, 512);
        k_vecdot<<<NN, 256, 0, stream>>>(vpb, x, vdot, hcatb);
        k_gemm<0, 1, 1><<<dim3(2, NN / 128), 256, 0, stream>>>(
            hcatb, xv_w1T + (size_t)l * 256 * 512, xv_b1 + l * HH, h1b, NN, 512, 256);
        k_gemm<0, 1, 0><<<dim3(6, NN / 128), 256, 0, stream>>>(
            h1b, xv_w2T + (size_t)l * 768 * 256, xv_b2 + l * 768, houtb, NN, 256, 768);
        bool last = (l == LL - 1);
        k_update_out<<<NN, 256, 0, stream>>>(
            houtb, vdot, vpb, x, vecM, vecA, vb,
            last ? nullptr : ln_w + (l + 1) * HH,
            last ? nullptr : ln_b + (l + 1) * HH, xlnb);
    }

    // ---- energy head ----
    k_gemm<0, 0, 1><<<dim3(1, NN / 128), 256, 0, stream>>>(
        xb, oe_w1T, oe_b1, heng, NN, 256, 128);
    k_zero<<<1, 256, 0, stream>>>(out, NGG / 4);
    k_energy2<<<32, 256, 0, stream>>>(heng, oe_w2, oe_b2, batch, out);
}

// Round 14
// 814.789 us; speedup vs baseline: 1.3908x; 1.0084x over previous
//
#include <hip/hip_runtime.h>
#include <hip/hip_bf16.h>
#include <math.h>

#define NN 8192
#define EE 131072
#define HH 256
#define LL 3
#define RR 128
#define NGG 64
#define MSG_WAVES 16         // waves per k_msg block (1024 threads)

typedef __attribute__((ext_vector_type(8))) short bf16x8;
typedef __attribute__((ext_vector_type(4))) float f32x4;
typedef unsigned short u16;

union U4 { ushort4 v; unsigned short a[4]; };
union U8 { uint4 v; unsigned short a[8]; };

__device__ __forceinline__ float silu(float v) { return v / (1.0f + expf(-v)); }
__device__ __forceinline__ float b2f(unsigned short u) { return __uint_as_float(((unsigned)u) << 16); }
__device__ __forceinline__ unsigned short f2b(float f) {
    unsigned u = __float_as_uint(f);
    u += 0x7fff + ((u >> 16) & 1);
    return (unsigned short)(u >> 16);
}

constexpr float kInvSqrt2 = 0.70710678118654752440f;
constexpr float kInvSqrt3 = 0.57735026918962576451f;
constexpr float kInvSqrtH = 0.0625f; // 1/sqrt(256)

// ---------------- utility ----------------
__global__ void k_zero(float* __restrict__ p, int n4) {
    int i = blockIdx.x * 256 + threadIdx.x;
    if (i < n4) ((float4*)p)[i] = make_float4(0.f, 0.f, 0.f, 0.f);
}

// ---------------- ALL weight prep in one launch ----------------
// transpose in[K,N] fp32 -> out[N,K] bf16, except rbf_w: straight cast (k-major kept)
__global__ __launch_bounds__(256) void k_wt_all(
    const float* __restrict__ xp_w1, const float* __restrict__ xp_w2,
    const float* __restrict__ rbf_w, const float* __restrict__ vec_w,
    const float* __restrict__ xv_w1, const float* __restrict__ xv_w2,
    const float* __restrict__ oe_w1,
    u16* __restrict__ xp_w1T, u16* __restrict__ xp_w2T, u16* __restrict__ rbf_wKb,
    u16* __restrict__ vec_wT, u16* __restrict__ xv_w1T, u16* __restrict__ xv_w2T,
    u16* __restrict__ oe_w1T) {
    int bid = blockIdx.x;
    const float* src; u16* dst; int K, N, t, cast = 0;
    if (bid < 2400) {
        int l = bid / 800, r = bid % 800;
        if (r < 64)       { src = xp_w1 + (size_t)l * 65536;  dst = xp_w1T + (size_t)l * 65536;  K = 256; N = 256; t = r; }
        else if (r < 256) { src = xp_w2 + (size_t)l * 196608; dst = xp_w2T + (size_t)l * 196608; K = 256; N = 768; t = r - 64; }
        else if (r < 352) { src = rbf_w + (size_t)l * 98304;  dst = rbf_wKb + (size_t)l * 98304; K = 128; N = 768; t = r - 256; cast = 1; }
        else if (r < 480) { src = vec_w + (size_t)l * 131072; dst = vec_wT + (size_t)l * 131072; K = 256; N = 512; t = r - 352; }
        else if (r < 608) { src = xv_w1 + (size_t)l * 131072; dst = xv_w1T + (size_t)l * 131072; K = 512; N = 256; t = r - 480; }
        else              { src = xv_w2 + (size_t)l * 196608; dst = xv_w2T + (size_t)l * 196608; K = 256; N = 768; t = r - 608; }
    } else {
        src = oe_w1; dst = oe_w1T; K = 256; N = 128; t = bid - 2400;
    }
    int nx = N >> 5;
    int bn = (t % nx) * 32, bk = (t / nx) * 32;
    int tx = threadIdx.x & 31, ty = threadIdx.x >> 5;   // 32 x 8
    if (cast) {
#pragma unroll
        for (int i = 0; i < 32; i += 8)
            dst[(size_t)(bk + ty + i) * N + bn + tx] = f2b(src[(size_t)(bk + ty + i) * N + bn + tx]);
        return;
    }
    __shared__ float tile[32][33];
#pragma unroll
    for (int i = 0; i < 32; i += 8)
        tile[ty + i][tx] = src[(size_t)(bk + ty + i) * N + bn + tx];
    __syncthreads();
#pragma unroll
    for (int i = 0; i < 32; i += 8)
        dst[(size_t)(bn + ty + i) * K + bk + tx] = f2b(tile[tx][ty + i]);
}

// ---------------- init: x = atom_emb[z], + LayerNorm(ln[0]) -> xlnb ----------------
__global__ void k_init_ln(const float* __restrict__ emb, const int* __restrict__ z,
                          const float* __restrict__ w, const float* __restrict__ b,
                          float* __restrict__ x, u16* __restrict__ xlnb) {
    int n = blockIdx.x, t = threadIdx.x;
    float v = emb[z[n] * HH + t];
    x[(size_t)n * HH + t] = v;
    float s = v, q = v * v;
#pragma unroll
    for (int m = 32; m >= 1; m >>= 1) {
        s += __shfl_xor(s, m, 64);
        q += __shfl_xor(q, m, 64);
    }
    __shared__ float s_sum[4], s_sq[4];
    int wid = t >> 6;
    if ((t & 63) == 0) { s_sum[wid] = s; s_sq[wid] = q; }
    __syncthreads();
    float S = s_sum[0] + s_sum[1] + s_sum[2] + s_sum[3];
    float Q = s_sq[0] + s_sq[1] + s_sq[2] + s_sq[3];
    float mu = S * (1.0f / HH);
    float var = Q * (1.0f / HH) - mu * mu;
    float rs = rsqrtf(var + 1e-5f);
    xlnb[(size_t)n * HH + t] = f2b((v - mu) * rs * w[t] + b[t]);
}

// ---------------- edge geometry ----------------
__global__ void k_edge_geom(const float* __restrict__ pos, const int* __restrict__ ei,
                            float* __restrict__ ev /*[E,4]*/) {
    int e = blockIdx.x * 256 + threadIdx.x;
    if (e >= EE) return;
    int s = ei[e], d = ei[EE + e];
    float rx = pos[s * 3 + 0] - pos[d * 3 + 0];
    float ry = pos[s * 3 + 1] - pos[d * 3 + 1];
    float rz = pos[s * 3 + 2] - pos[d * 3 + 2];
    float dist = sqrtf(rx * rx + ry * ry + rz * rz);
    float inv = 1.0f / dist;
    ((float4*)ev)[e] = make_float4(rx * inv, ry * inv, rz * inv, dist);
}

// ---------------- CSR build ----------------
__global__ void k_hist(const int* __restrict__ ei, int* __restrict__ deg) {
    int e = blockIdx.x * 256 + threadIdx.x;
    if (e < EE) atomicAdd(&deg[ei[EE + e]], 1);
}
__global__ void k_scan(const int* __restrict__ deg, int* __restrict__ row_ptr,
                       int* __restrict__ fill) {
    __shared__ int buf[256];
    __shared__ int carry_s;
    int t = threadIdx.x;
    if (t == 0) carry_s = 0;
    __syncthreads();
    for (int r = 0; r < NN; r += 256) {
        int v = deg[r + t];
        buf[t] = v;
        __syncthreads();
        for (int ofs = 1; ofs < 256; ofs <<= 1) {
            int add = (t >= ofs) ? buf[t - ofs] : 0;
            __syncthreads();
            buf[t] += add;
            __syncthreads();
        }
        int excl = buf[t] - v;
        int carry = carry_s;
        row_ptr[r + t] = carry + excl;
        fill[r + t] = carry + excl;
        __syncthreads();
        if (t == 255) carry_s = carry + buf[t];
        __syncthreads();
    }
    if (t == 0) row_ptr[NN] = carry_s;
}
// degree bucket-sort (descending) -> dorder: balances waves within k_msg blocks
__global__ void k_sort(const int* __restrict__ deg, int* __restrict__ dorder) {
    __shared__ int bins[256];
    __shared__ int base[256];
    int t = threadIdx.x;              // 256 threads, single block
    bins[t] = 0;
    __syncthreads();
    for (int d = t; d < NN; d += 256) {
        int b = deg[d]; b = b > 255 ? 255 : b;
        atomicAdd(&bins[b], 1);
    }
    __syncthreads();
    if (t == 0) {
        int acc = 0;
        for (int k = 255; k >= 0; --k) { base[k] = acc; acc += bins[k]; }
    }
    __syncthreads();
    bins[t] = 0;
    __syncthreads();
    for (int d = t; d < NN; d += 256) {
        int b = deg[d]; b = b > 255 ? 255 : b;
        int p = atomicAdd(&bins[b], 1);
        dorder[base[b] + p] = d;
    }
}
// scatter + fused per-edge gaussian window table (8 rows, k0 clamp [0,120])
__global__ void k_scatter(const int* __restrict__ ei, const float* __restrict__ ev,
                          int* __restrict__ fill, int* __restrict__ srcp,
                          float4* __restrict__ evp, int* __restrict__ k0tab,
                          float* __restrict__ gtab) {
    int e = blockIdx.x * 256 + threadIdx.x;
    if (e >= EE) return;
    int d = ei[EE + e];
    int pos = atomicAdd(&fill[d], 1);
    float4 e4 = ((const float4*)ev)[e];
    srcp[pos] = ei[e];
    evp[pos] = e4;
    const float step = 12.0f / 127.0f;
    const float coeff = -0.5f / (step * step);
    float dist = e4.w;
    int k0 = (int)floorf(dist / step) - 3;
    k0 = k0 < 0 ? 0 : (k0 > 120 ? 120 : k0);
    float g[8];
#pragma unroll
    for (int k = 0; k < 8; ++k) {
        float t = dist - (k0 + k) * step;
        g[k] = expf(coeff * t * t);
    }
    k0tab[pos] = k0;
    ((float4*)gtab)[pos * 2 + 0] = make_float4(g[0], g[1], g[2], g[3]);
    ((float4*)gtab)[pos * 2 + 1] = make_float4(g[4], g[5], g[6], g[7]);
}

// ---------------- bf16 MFMA GEMM: C = act(A[M,K] @ BT[N,K]^T + bias) ----------------
template <int AF32, int OUT_BF16, int ACT>
__global__ __launch_bounds__(256) void k_gemm(
    const void* __restrict__ Av, const u16* __restrict__ BT,
    const float* __restrict__ bias, void* __restrict__ C, int M, int K, int N) {
    __shared__ uint4 As4[512];
    __shared__ uint4 Bs4[512];
    u16* As = (u16*)As4;
    u16* Bs = (u16*)Bs4;
    int tid = threadIdx.x;
    int wave = tid >> 6, lane = tid & 63;
    int bm = blockIdx.y * 128, bn = blockIdx.x * 128;
    int wm = (wave >> 1) * 64, wn = (wave & 1) * 64;
    int lm = lane & 15;
    int kg = lane >> 4;
    f32x4 acc[4][4] = {};

    for (int k0 = 0; k0 < K; k0 += 32) {
#pragma unroll
        for (int it = 0; it < 2; ++it) {
            int idx = it * 256 + tid;
            int r = idx >> 2, seg = idx & 3;
            if (AF32) {
                const float* Af = (const float*)Av;
                float4 fa = *(const float4*)&Af[(size_t)(bm + r) * K + k0 + seg * 8];
                float4 fb = *(const float4*)&Af[(size_t)(bm + r) * K + k0 + seg * 8 + 4];
                U8 u;
                u.a[0] = f2b(fa.x); u.a[1] = f2b(fa.y); u.a[2] = f2b(fa.z); u.a[3] = f2b(fa.w);
                u.a[4] = f2b(fb.x); u.a[5] = f2b(fb.y); u.a[6] = f2b(fb.z); u.a[7] = f2b(fb.w);
                As4[idx] = u.v;
            } else {
                const u16* A = (const u16*)Av;
                As4[idx] = *(const uint4*)&A[(size_t)(bm + r) * K + k0 + seg * 8];
            }
            Bs4[idx] = *(const uint4*)&BT[(size_t)(bn + r) * K + k0 + seg * 8];
        }
        __syncthreads();
        bf16x8 af[4], bfr[4];
#pragma unroll
        for (int i = 0; i < 4; ++i)
            af[i] = *(const bf16x8*)&As[(wm + i * 16 + lm) * 32 + kg * 8];
#pragma unroll
        for (int j = 0; j < 4; ++j)
            bfr[j] = *(const bf16x8*)&Bs[(wn + j * 16 + lm) * 32 + kg * 8];
#pragma unroll
        for (int i = 0; i < 4; ++i)
#pragma unroll
            for (int j = 0; j < 4; ++j)
                acc[i][j] = __builtin_amdgcn_mfma_f32_16x16x32_bf16(af[i], bfr[j], acc[i][j], 0, 0, 0);
        __syncthreads();
    }

#pragma unroll
    for (int j = 0; j < 4; ++j) {
        int col = bn + wn + j * 16 + lm;
        float bv = bias ? bias[col] : 0.f;
#pragma unroll
        for (int i = 0; i < 4; ++i) {
            int row0 = bm + wm + i * 16 + kg * 4;
#pragma unroll
            for (int r = 0; r < 4; ++r) {
                float v = acc[i][j][r] + bv;
                if (ACT) v = silu(v);
                if (OUT_BF16)
                    ((u16*)C)[(size_t)(row0 + r) * N + col] = f2b(v);
                else
                    ((float*)C)[(size_t)(row0 + r) * N + col] = v;
            }
        }
    }
}

// ---------------- fused message pass v9: 16-wave panel blocks, degree-sorted dsts --
// Blocks take 16 consecutive dsts from the degree-sorted order -> waves within a
// block have near-equal degree, eliminating barrier straggle at the 3 panel syncs.
__global__ __launch_bounds__(1024) void k_msg(
    const u16* __restrict__ xhb, const u16* __restrict__ vinb,
    const int* __restrict__ srcp, const float4* __restrict__ evp,
    const int* __restrict__ row_ptr, const int* __restrict__ k0tab,
    const float* __restrict__ gtab, const u16* __restrict__ WK /*[128][768] bf16*/,
    const float* __restrict__ rbias, float* __restrict__ x,
    const float* __restrict__ vin, float* __restrict__ vecM,
    const int* __restrict__ dorder) {
    __shared__ u16 Wp[128 * 256];   // 64 KB panel
    int tid = threadIdx.x;
    int wave = tid >> 6, lane = tid & 63;
    int c0 = lane * 4;
    int d = dorder[blockIdx.x * MSG_WAVES + wave];   // degree-sorted dst
    int E0 = row_ptr[d], E1 = row_ptr[d + 1];
    float accv[3][4] = {};          // persists across panels 1,2

#pragma unroll
    for (int p = 0; p < 3; ++p) {
        __syncthreads();
#pragma unroll
        for (int it = 0; it < 4; ++it) {        // cooperative 64KB panel load
            int idx = it * 1024 + tid;          // 4096 uint4s
            int row = idx >> 5;
            int col8 = (idx & 31) * 8;
            *(uint4*)&Wp[row * 256 + col8] =
                *(const uint4*)&WK[(size_t)row * 768 + p * 256 + col8];
        }
        __syncthreads();
        float4 bb = ((const float4*)(rbias + p * 256))[lane];
        float bias4[4] = {bb.x, bb.y, bb.z, bb.w};
        float accx[4] = {};
        for (int j = E0; j < E1; ++j) {
            int s = srcp[j];
            int kj = k0tab[j];
            float4 ga = ((const float4*)gtab)[(size_t)j * 2 + 0];
            float4 gb = ((const float4*)gtab)[(size_t)j * 2 + 1];
            float g[8] = {ga.x, ga.y, ga.z, ga.w, gb.x, gb.y, gb.z, gb.w};
            float rr[4] = {bias4[0], bias4[1], bias4[2], bias4[3]};
#pragma unroll
            for (int k = 0; k < 8; ++k) {
                U4 w;
                w.v = *(const ushort4*)&Wp[(kj + k) * 256 + c0];
#pragma unroll
                for (int c = 0; c < 4; ++c) rr[c] += g[k] * b2f(w.a[c]);
            }
            if (p == 0) {
                U4 X; X.v = *(const ushort4*)(xhb + (size_t)s * 768 + c0);
#pragma unroll
                for (int c = 0; c < 4; ++c) accx[c] += b2f(X.a[c]) * rr[c];
            } else if (p == 1) {
                U4 X, V0, V1, V2;
                X.v = *(const ushort4*)(xhb + (size_t)s * 768 + 256 + c0);
                V0.v = *(const ushort4*)(vinb + (size_t)s * 768 + c0);
                V1.v = *(const ushort4*)(vinb + (size_t)s * 768 + 256 + c0);
                V2.v = *(const ushort4*)(vinb + (size_t)s * 768 + 512 + c0);
#pragma unroll
                for (int c = 0; c < 4; ++c) {
                    float m1 = b2f(X.a[c]) * rr[c] * kInvSqrt3;
                    accv[0][c] += b2f(V0.a[c]) * m1;
                    accv[1][c] += b2f(V1.a[c]) * m1;
                    accv[2][c] += b2f(V2.a[c]) * m1;
                }
            } else {
                U4 X; X.v = *(const ushort4*)(xhb + (size_t)s * 768 + 512 + c0);
                float4 ev4 = evp[j];
#pragma unroll
                for (int c = 0; c < 4; ++c) {
                    float m2 = b2f(X.a[c]) * rr[c];
                    accv[0][c] += m2 * ev4.x;
                    accv[1][c] += m2 * ev4.y;
                    accv[2][c] += m2 * ev4.z;
                }
            }
        }
        if (p == 0) {
            size_t xi = (size_t)d * 256 + c0;
            float4 xv = *(const float4*)&x[xi];
            xv.x = (xv.x + accx[0]) * kInvSqrt2;
            xv.y = (xv.y + accx[1]) * kInvSqrt2;
            xv.z = (xv.z + accx[2]) * kInvSqrt2;
            xv.w = (xv.w + accx[3]) * kInvSqrt2;
            *(float4*)&x[xi] = xv;
        }
    }
    // epilogue: vecM = vin + dvec * invSqrtH
#pragma unroll
    for (int k = 0; k < 3; ++k) {
        size_t idx = (size_t)d * 768 + k * 256 + c0;
        float4 vv = *(const float4*)&vin[idx];
        vv.x += accv[k][0] * kInvSqrtH;
        vv.y += accv[k][1] * kInvSqrtH;
        vv.z += accv[k][2] * kInvSqrtH;
        vv.w += accv[k][3] * kInvSqrtH;
        *(float4*)&vecM[idx] = vv;
    }
}

// ---------------- vec_dot + hcat(bf16) = [x, vnorm]; vp in bf16 -------------------
__global__ void k_vecdot(const u16* __restrict__ vp, const float* __restrict__ x,
                         float* __restrict__ vec_dot, u16* __restrict__ hcat) {
    int i = blockIdx.x * 256 + threadIdx.x;  // N*H
    int n = i >> 8, c = i & 255;
    const u16* p = vp + (size_t)n * 1536;
    float dsum = 0.f, qsum = 0.f;
#pragma unroll
    for (int k = 0; k < 3; ++k) {
        float v1 = b2f(p[k * 512 + c]);
        float v2 = b2f(p[k * 512 + 256 + c]);
        dsum += v1 * v2;
        qsum += v2 * v2;
    }
    vec_dot[i] = dsum * kInvSqrtH;
    hcat[(size_t)n * 512 + c] = f2b(x[i]);
    hcat[(size_t)n * 512 + 256 + c] = f2b(sqrtf(qsum + 1e-8f));
}

// ---------------- update epilogue + fused LayerNorm for next layer ----------------
__global__ void k_update_out(const u16* __restrict__ hout, const float* __restrict__ vec_dot,
                             const u16* __restrict__ vp, float* __restrict__ x,
                             const float* __restrict__ vecM, float* __restrict__ vfin,
                             u16* __restrict__ vb,
                             const float* __restrict__ lnw, const float* __restrict__ lnb,
                             u16* __restrict__ xout) {
    int n = blockIdx.x, t = threadIdx.x;
    size_t i = (size_t)n * 256 + t;
    float xv1 = b2f(hout[(size_t)n * 768 + t]);
    float xv2 = b2f(hout[(size_t)n * 768 + 256 + t]);
    float xv3 = b2f(hout[(size_t)n * 768 + 512 + t]);
    float dxv = (xv1 + xv2 * vec_dot[i]) * kInvSqrt2;
    float nx = (x[i] + dxv) * kInvSqrt2;
    x[i] = nx;
#pragma unroll
    for (int k = 0; k < 3; ++k) {
        size_t idx = (size_t)n * 768 + k * 256 + t;
        float nv = vecM[idx] + xv3 * b2f(vp[(size_t)n * 1536 + k * 512 + t]);
        vfin[idx] = nv;
        vb[idx] = f2b(nv);
    }
    if (lnw) {
        float s = nx, q = nx * nx;
#pragma unroll
        for (int m = 32; m >= 1; m >>= 1) {
            s += __shfl_xor(s, m, 64);
            q += __shfl_xor(q, m, 64);
        }
        __shared__ float s_sum[4], s_sq[4];
        int wid = t >> 6;
        if ((t & 63) == 0) { s_sum[wid] = s; s_sq[wid] = q; }
        __syncthreads();
        float S = s_sum[0] + s_sum[1] + s_sum[2] + s_sum[3];
        float Q = s_sq[0] + s_sq[1] + s_sq[2] + s_sq[3];
        float mu = S * (1.0f / HH);
        float var = Q * (1.0f / HH) - mu * mu;
        float rs = rsqrtf(var + 1e-5f);
        xout[i] = f2b((nx - mu) * rs * lnw[t] + lnb[t]);
    } else {
        xout[i] = f2b(nx);
    }
}

// ---------------- energy reduce ----------------
__global__ void k_energy2(const float* __restrict__ h, const float* __restrict__ w2,
                          const float* __restrict__ b2, const int* __restrict__ batch,
                          float* __restrict__ out) {
    __shared__ float g[NGG];
    int t = threadIdx.x;
    if (t < NGG) g[t] = 0.f;
    __syncthreads();
    int a = blockIdx.x * 256 + t;
    const float4* hr = (const float4*)(h + (size_t)a * 128);
    const float4* w4 = (const float4*)w2;
    float acc = 0.f;
#pragma unroll 8
    for (int i = 0; i < 32; ++i) {
        float4 hv = hr[i], wv = w4[i];
        acc += hv.x * wv.x + hv.y * wv.y + hv.z * wv.z + hv.w * wv.w;
    }
    acc += b2[0];
    atomicAdd(&g[batch[a]], acc);
    __syncthreads();
    if (t < NGG && g[t] != 0.f) atomicAdd(&out[t], g[t]);
}

extern "C" void kernel_launch(void* const* d_in, const int* in_sizes, int n_in,
                              void* d_out, int out_size, void* d_ws, size_t ws_size,
                              hipStream_t stream) {
    const float* pos      = (const float*)d_in[0];
    const float* atom_emb = (const float*)d_in[1];
    const float* ln_w     = (const float*)d_in[2];
    const float* ln_b     = (const float*)d_in[3];
    const float* xp_w1    = (const float*)d_in[4];
    const float* xp_b1    = (const float*)d_in[5];
    const float* xp_w2    = (const float*)d_in[6];
    const float* xp_b2    = (const float*)d_in[7];
    const float* rbf_w    = (const float*)d_in[8];
    const float* rbf_b    = (const float*)d_in[9];
    const float* vec_w    = (const float*)d_in[10];
    const float* xv_w1    = (const float*)d_in[11];
    const float* xv_b1    = (const float*)d_in[12];
    const float* xv_w2    = (const float*)d_in[13];
    const float* xv_b2    = (const float*)d_in[14];
    const float* oe_w1    = (const float*)d_in[15];
    const float* oe_b1    = (const float*)d_in[16];
    const float* oe_w2    = (const float*)d_in[17];
    const float* oe_b2    = (const float*)d_in[18];
    const int*   z        = (const int*)d_in[19];
    const int*   ei       = (const int*)d_in[20];
    const int*   batch    = (const int*)d_in[21];
    float* out = (float*)d_out;

    char* ws = (char*)d_ws;
    size_t off = 0;
    auto alloc = [&](size_t b) {
        void* p = ws + off;
        off = (off + b + 255) & ~(size_t)255;
        return p;
    };
    float*  x      = (float*)alloc((size_t)NN * HH * 4);       //   8 MB
    float*  vecA   = (float*)alloc((size_t)NN * 768 * 4);      //  24 MB  \ adjacent:
    u16*    vb     = (u16*)alloc((size_t)NN * 768 * 2);        //  12 MB  / joint zero
    float*  vecM   = (float*)alloc((size_t)NN * 768 * 4);      //  24 MB
    u16*    xlnb   = (u16*)alloc((size_t)NN * HH * 2);         //   4 MB (alias xb)
    u16*    t1b    = (u16*)alloc((size_t)NN * HH * 2);         //   4 MB (alias h1b)
    u16*    xhb    = (u16*)alloc((size_t)NN * 768 * 2);        //  12 MB (alias hcatb)
    float*  vdot   = (float*)alloc((size_t)NN * HH * 4);       //   8 MB (alias heng)
    u16*    vpb    = (u16*)alloc((size_t)NN * 1536 * 2);       //  24 MB
    u16*    houtb  = (u16*)alloc((size_t)NN * 768 * 2);        //  12 MB
    float*  ev     = (float*)alloc((size_t)EE * 4 * 4);        //   2 MB
    int*    deg    = (int*)alloc((size_t)NN * 4);
    int*    row_ptr= (int*)alloc((size_t)(NN + 1) * 4);
    int*    fill   = (int*)alloc((size_t)NN * 4);
    int*    dorder = (int*)alloc((size_t)NN * 4);
    int*    srcp   = (int*)alloc((size_t)EE * 4);
    float4* evp    = (float4*)alloc((size_t)EE * 16);          //   2 MB
    int*    k0tab  = (int*)alloc((size_t)EE * 4);              // 0.5 MB
    float*  gtab   = (float*)alloc((size_t)EE * 8 * 4);        //   4 MB
    u16* xp_w1T   = (u16*)alloc((size_t)3 * 256 * 256 * 2);
    u16* xp_w2T   = (u16*)alloc((size_t)3 * 768 * 256 * 2);
    u16* rbf_wKb  = (u16*)alloc((size_t)3 * 128 * 768 * 2);    // k-major bf16 cast
    u16* vec_wT   = (u16*)alloc((size_t)3 * 512 * 256 * 2);
    u16* xv_w1T   = (u16*)alloc((size_t)3 * 256 * 512 * 2);
    u16* xv_w2T   = (u16*)alloc((size_t)3 * 768 * 256 * 2);
    u16* oe_w1T   = (u16*)alloc((size_t)128 * 256 * 2);
    (void)ws_size;

    u16*   h1b   = t1b;
    u16*   hcatb = xhb;
    float* heng  = vdot;
    u16*   xb    = xlnb;

    // ---- setup ----
    k_wt_all<<<2432, 256, 0, stream>>>(xp_w1, xp_w2, rbf_w, vec_w, xv_w1, xv_w2, oe_w1,
                                       xp_w1T, xp_w2T, rbf_wKb, vec_wT, xv_w1T, xv_w2T, oe_w1T);
    k_zero<<<(36 * 1024 * 1024 / 16 + 255) / 256, 256, 0, stream>>>(vecA, 36 * 1024 * 1024 / 16);
    k_zero<<<8, 256, 0, stream>>>((float*)deg, NN / 4);
    k_init_ln<<<NN, 256, 0, stream>>>(atom_emb, z, ln_w, ln_b, x, xlnb);
    k_edge_geom<<<EE / 256, 256, 0, stream>>>(pos, ei, ev);
    k_hist<<<EE / 256, 256, 0, stream>>>(ei, deg);
    k_scan<<<1, 256, 0, stream>>>(deg, row_ptr, fill);
    k_sort<<<1, 256, 0, stream>>>(deg, dorder);
    k_scatter<<<EE / 256, 256, 0, stream>>>(ei, ev, fill, srcp, evp, k0tab, gtab);

    for (int l = 0; l < LL; ++l) {
        // ---- PaiNNMessage ----
        k_gemm<0, 1, 1><<<dim3(2, NN / 128), 256, 0, stream>>>(
            xlnb, xp_w1T + (size_t)l * 256 * 256, xp_b1 + l * HH, t1b, NN, 256, 256);
        k_gemm<0, 1, 0><<<dim3(6, NN / 128), 256, 0, stream>>>(
            t1b, xp_w2T + (size_t)l * 768 * 256, xp_b2 + l * 768, xhb, NN, 256, 768);
        k_msg<<<NN / MSG_WAVES, 1024, 0, stream>>>(
            xhb, vb, srcp, evp, row_ptr, k0tab, gtab,
            rbf_wKb + (size_t)l * 128 * 768, rbf_b + l * 768, x, vecA, vecM, dorder);

        // ---- PaiNNUpdate ----
        k_gemm<1, 1, 0><<<dim3(4, 3 * NN / 128), 256, 0, stream>>>(
            vecM, vec_wT + (size_t)l * 512 * 256, nullptr, vpb, 3 * NN, 256, 512);
        k_vecdot<<<NN, 256, 0, stream>>>(vpb, x, vdot, hcatb);
        k_gemm<0, 1, 1><<<dim3(2, NN / 128), 256, 0, stream>>>(
            hcatb, xv_w1T + (size_t)l * 256 * 512, xv_b1 + l * HH, h1b, NN, 512, 256);
        k_gemm<0, 1, 0><<<dim3(6, NN / 128), 256, 0, stream>>>(
            h1b, xv_w2T + (size_t)l * 768 * 256, xv_b2 + l * 768, houtb, NN, 256, 768);
        bool last = (l == LL - 1);
        k_update_out<<<NN, 256, 0, stream>>>(
            houtb, vdot, vpb, x, vecM, vecA, vb,
            last ? nullptr : ln_w + (l + 1) * HH,
            last ? nullptr : ln_b + (l + 1) * HH, xlnb);
    }

    // ---- energy head ----
    k_gemm<0, 0, 1><<<dim3(1, NN / 128), 256, 0, stream>>>(
        xb, oe_w1T, oe_b1, heng, NN, 256, 128);
    k_zero<<<1, 256, 0, stream>>>(out, NGG / 4);
    k_energy2<<<32, 256, 0, stream>>>(heng, oe_w2, oe_b2, batch, out);
}